// Round 9
// baseline (259.671 us; speedup 1.0000x reference)
//
#include <hip/hip_runtime.h>
#include <stdint.h>

constexpr int Bn = 8, Nn = 4096, Sn = 1024, Cc = 64, KNN = 32, C1 = 128, C2 = 256;
constexpr int Qq = Bn * Sn;     // 8192 queries
constexpr int Mm = Qq * KNN;    // 262144 samples
constexpr int OUT_XYZ = Bn * Sn * 3;  // 24576 floats (output 0)
constexpr float BNEPS = 1e-5f;

// ---------- ws layout ----------
constexpr size_t SZ_IDX  = (size_t)Qq * KNN * 4;        // 1 MB
constexpr size_t SZ_PTST = (size_t)Bn * Nn * Cc * 2;    // 4 MB (bf16)
constexpr int    NB_MLP  = Mm / 64;                     // 4096 blocks
constexpr size_t SZ_P1   = (size_t)NB_MLP * 256 * 4;    // 4 MB
constexpr size_t SZ_P2   = (size_t)NB_MLP * 512 * 4;    // 8 MB
constexpr size_t OFF_IDX  = 0;
constexpr size_t OFF_PTST = OFF_IDX + SZ_IDX;
constexpr size_t OFF_P1   = OFF_PTST + SZ_PTST;
constexpr size_t OFF_P2   = OFF_P1 + SZ_P1;
constexpr size_t OFF_P1B  = OFF_P2 + SZ_P2;
constexpr size_t OFF_P2B  = OFF_P1B + (size_t)128 * 256 * 4;
constexpr size_t OFF_BN1  = OFF_P2B + (size_t)128 * 512 * 4;
constexpr size_t OFF_BN2  = OFF_BN1 + 1024;
constexpr size_t OFF_W2F  = OFF_BN2 + 2048;                  // 64 KB
constexpr size_t OFF_W1F  = OFF_W2F + (size_t)32768 * 2;     // 24 KB
constexpr size_t OFF_Y1   = (OFF_W1F + (size_t)12288 * 2 + 255) & ~(size_t)255;
// total ws need ≈ OFF_Y1 + 67 MB

typedef __attribute__((ext_vector_type(8))) __bf16 bf16x8;
typedef __attribute__((ext_vector_type(4))) float f32x4;

__device__ __forceinline__ unsigned short f2bf(float f) {
  unsigned u = __float_as_uint(f);
  u = u + 0x7FFFu + ((u >> 16) & 1u);   // RNE
  return (unsigned short)(u >> 16);
}

// ---------- fused prep: ptsT->bf16 | copy new_xyz | W1 frags | W2 frags ----------
__global__ __launch_bounds__(256) void k_prep(const float* __restrict__ pts,
                                              const float* __restrict__ nxyz,
                                              const float* __restrict__ W1,
                                              const float* __restrict__ W2,
                                              unsigned short* __restrict__ ptsTbf,
                                              float* __restrict__ outdst,
                                              unsigned short* __restrict__ w1f,
                                              unsigned short* __restrict__ w2f) {
  int blk = blockIdx.x, t = threadIdx.x;
  if (blk < 512) {                       // points [B,C,N] f32 -> [B,N,C] bf16
    __shared__ float tile[64][65];
    int b = blk >> 6, n0 = (blk & 63) * 64;
    int cl = t & 63, rw = t >> 6;
#pragma unroll
    for (int i = 0; i < 16; ++i) {
      int c = i * 4 + rw;
      tile[cl][c] = pts[((size_t)b * Cc + c) * Nn + n0 + cl];
    }
    __syncthreads();
#pragma unroll
    for (int i = 0; i < 16; ++i) {
      int nf = i * 4 + rw;
      ptsTbf[((size_t)b * Nn + n0 + nf) * Cc + cl] = f2bf(tile[nf][cl]);
    }
  } else if (blk < 608) {                // copy new_xyz to output 0
    int i = t + (blk - 512) * 256;
    if (i < OUT_XYZ) outdst[i] = nxyz[i];
  } else if (blk < 656) {                // W1 [128,70] -> bf16 B-frags, K pad 96
    int u = t + (blk - 608) * 256;       // 12288 total
    int j = u & 7, lane = (u >> 3) & 63, rest = u >> 9;
    int ks = rest % 3, nt = rest / 3;
    int ch = nt * 16 + (lane & 15);
    int k = ks * 32 + (lane >> 4) * 8 + j;
    w1f[u] = (k < 70) ? f2bf(W1[ch * 70 + k]) : (unsigned short)0;
  } else {                               // W2 [256,128] -> bf16 B-frags
    int u = t + (blk - 656) * 256;       // 32768 total
    int j = u & 7, lane = (u >> 3) & 63, ks = (u >> 9) & 3, ntile = u >> 11;
    int col = ntile * 16 + (lane & 15);
    int k = ks * 32 + (lane >> 4) * 8 + j;
    w2f[u] = f2bf(W2[col * C1 + k]);
  }
}

// ---------- kNN: wave-extracted thresholds + two-tier compact + readlane rank ----------
// Distance bits replicate the reference evaluation (norms plain mul/add, dot FMA
// chain, (A+B)-2*dot) under `fp contract(off)`. U1 is a speed heuristic; U2 is
// GUARANTEED to admit >=32 keys (each wave contributes >=8 samples <= its 8th
// extraction, samples subset of keys). Fast path needs cnt>=K (superset proof);
// exact u64 (key<<32|idx) ranking reproduces top_k tie-break. Fallback: radix.
__global__ __launch_bounds__(256) void k_knn(const float* __restrict__ xyz,
                                             const float* __restrict__ nxyz,
                                             int* __restrict__ idxout) {
  int q = blockIdx.x, b = q >> 10, t = threadIdx.x;
  int lane = t & 63, w = t >> 6;
  const float* xb = xyz + (size_t)b * Nn * 3;
  float qx = nxyz[q * 3 + 0], qy = nxyz[q * 3 + 1], qz = nxyz[q * 3 + 2];
  unsigned key[16];
  {
#pragma clang fp contract(off)
    float sqq = (qx * qx + qy * qy) + qz * qz;
#pragma unroll
    for (int i = 0; i < 16; ++i) {
      int p = t + (i << 8);
      float xl = xb[p * 3 + 0], yl = xb[p * 3 + 1], zl = xb[p * 3 + 2];
      float sqp = (xl * xl + yl * yl) + zl * zl;
      float dot = __builtin_fmaf(qz, zl, __builtin_fmaf(qy, yl, qx * xl));
      float d = (sqq + sqp) - 2.0f * dot;
      unsigned u = __float_as_uint(d);
      key[i] = (u & 0x80000000u) ? ~u : (u | 0x80000000u);   // monotone map
    }
  }
  __shared__ unsigned long long buf[1024];   // [0,512) tier1, [512,1024) tier2
  __shared__ unsigned wthr[8];
  __shared__ unsigned cnt1, cnt2, ovf;
  __shared__ unsigned hist[256];             // fallback
  __shared__ unsigned wsum[4];
  __shared__ unsigned sel_bin, sel_off, eqcnt;
  __shared__ int eqbuf[128];

  if (t == 0) { cnt1 = 0; cnt2 = 0; ovf = 0; }
  // per-wave: extract 8 smallest of this wave's 64 sampled keys (key[0])
  {
    unsigned v = key[0];
    unsigned s2v = 0xFFFFFFFFu, s7v = 0xFFFFFFFFu;
#pragma unroll
    for (int r = 0; r < 8; ++r) {
      unsigned m = v;
#pragma unroll
      for (int off = 32; off >= 1; off >>= 1) {
        unsigned o = (unsigned)__shfl_xor((int)m, off);
        m = (o < m) ? o : m;
      }
      if (r == 2) s2v = m;
      if (r == 7) s7v = m;
      if (v == m) v = 0xFFFFFFFFu;
    }
    if (lane == 0) { wthr[w] = s2v; wthr[4 + w] = s7v; }
  }
  __syncthreads();
  unsigned U1, U2;
  {
    unsigned a0 = wthr[0], a1 = wthr[1], a2 = wthr[2], a3 = wthr[3];
    U1 = min(min(a0, a1), min(a2, a3));
    unsigned b0 = wthr[4], b1 = wthr[5], b2 = wthr[6], b3 = wthr[7];
    unsigned mx = max(max(b0, b1), max(b2, b3));
    U2 = (mx == 0xFFFFFFFFu) ? 0xFFFFFFFFu : (mx + 1u);
  }
  // two-tier compaction (ballot-aggregated, 1 atomic per wave per tier per iter)
#pragma unroll
  for (int i = 0; i < 16; ++i) {
    unsigned k = key[i];
    bool t1 = k < U1;
    bool t2 = !t1 && k < U2;
    unsigned long long m1 = __ballot(t1);
    if (m1 != 0ull) {
      unsigned base = 0;
      if (lane == 0) base = atomicAdd(&cnt1, (unsigned)__popcll(m1));
      base = (unsigned)__shfl((int)base, 0);
      if (t1) {
        unsigned off = base + (unsigned)__popcll(m1 & ((1ull << lane) - 1ull));
        if (off < 512u)
          buf[off] = ((unsigned long long)k << 32) | (unsigned)(t + (i << 8));
        else
          ovf = 1;
      }
    }
    unsigned long long m2 = __ballot(t2);
    if (m2 != 0ull) {
      unsigned base = 0;
      if (lane == 0) base = atomicAdd(&cnt2, (unsigned)__popcll(m2));
      base = (unsigned)__shfl((int)base, 0);
      if (t2) {
        unsigned off = base + (unsigned)__popcll(m2 & ((1ull << lane) - 1ull));
        if (off < 512u)
          buf[512 + off] = ((unsigned long long)k << 32) | (unsigned)(t + (i << 8));
        else
          ovf = 1;
      }
    }
  }
  __syncthreads();
  unsigned n1 = cnt1, n2 = cnt2;
  int nc = (n1 >= (unsigned)KNN) ? (int)n1 : (int)(n1 + n2);
  bool ok = (!ovf) && (n1 + n2 >= (unsigned)KNN) && (nc <= 768);
  if (ok) {
    int lim = (n1 >= (unsigned)KNN) ? (int)n1 : -1;  // -1: two-tier mapping active
    int n1i = (int)n1;
    auto amap = [&](int ci) { return (lim >= 0 || ci < n1i) ? ci : 512 + (ci - n1i); };
    int nchunk = (nc + 63) >> 6;
    if (nc <= 256) {
      unsigned long long my0 = (t < nc) ? buf[amap(t)] : ~0ull;
      int r0 = 0;
      for (int c = 0; c < nchunk; ++c) {
        int ci = c * 64 + lane;
        unsigned long long v = (ci < nc) ? buf[amap(ci)] : ~0ull;
        unsigned vlo = (unsigned)v, vhi = (unsigned)(v >> 32);
#pragma unroll
        for (int i = 0; i < 64; ++i) {
          unsigned olo = __builtin_amdgcn_readlane(vlo, i);
          unsigned ohi = __builtin_amdgcn_readlane(vhi, i);
          unsigned long long o = ((unsigned long long)ohi << 32) | olo;
          r0 += (o < my0);
        }
      }
      if (t < nc && r0 < KNN) idxout[q * KNN + r0] = (int)(unsigned)(my0 & 0xFFFFFFFFull);
    } else {
      unsigned long long my0 = (t < nc) ? buf[amap(t)] : ~0ull;
      unsigned long long my1 = (t + 256 < nc) ? buf[amap(t + 256)] : ~0ull;
      unsigned long long my2 = (t + 512 < nc) ? buf[amap(t + 512)] : ~0ull;
      int r0 = 0, r1 = 0, r2 = 0;
      for (int c = 0; c < nchunk; ++c) {
        int ci = c * 64 + lane;
        unsigned long long v = (ci < nc) ? buf[amap(ci)] : ~0ull;
        unsigned vlo = (unsigned)v, vhi = (unsigned)(v >> 32);
#pragma unroll
        for (int i = 0; i < 64; ++i) {
          unsigned olo = __builtin_amdgcn_readlane(vlo, i);
          unsigned ohi = __builtin_amdgcn_readlane(vhi, i);
          unsigned long long o = ((unsigned long long)ohi << 32) | olo;
          r0 += (o < my0); r1 += (o < my1); r2 += (o < my2);
        }
      }
      if (r0 < KNN) idxout[q * KNN + r0] = (int)(unsigned)(my0 & 0xFFFFFFFFull);
      if (r1 < KNN) idxout[q * KNN + r1] = (int)(unsigned)(my1 & 0xFFFFFFFFull);
      if (r2 < KNN) idxout[q * KNN + r2] = (int)(unsigned)(my2 & 0xFFFFFFFFull);
    }
  } else {
    // fallback: full 4-pass radix (round-4 proven path)
    unsigned prefix = 0, remaining = (unsigned)KNN;
    if (t == 0) { cnt1 = 0; eqcnt = 0; }
#pragma unroll
    for (int shift = 24; shift >= 0; shift -= 8) {
      hist[t] = 0;
      __syncthreads();
      unsigned himask = (shift == 24) ? 0u : (0xFFFFFFFFu << ((shift + 8) & 31));
#pragma unroll
      for (int i = 0; i < 16; ++i)
        if ((key[i] & himask) == prefix)
          atomicAdd(&hist[(key[i] >> shift) & 255], 1u);
      __syncthreads();
      unsigned h = hist[t], v = h;
#pragma unroll
      for (int off = 1; off < 64; off <<= 1) {
        unsigned o = __shfl_up(v, off);
        if (lane >= off) v += o;
      }
      if (lane == 63) wsum[w] = v;
      __syncthreads();
      unsigned woff = 0;
      for (int ww = 0; ww < w; ++ww) woff += wsum[ww];
      v += woff;
      unsigned vex = v - h;
      if (vex < remaining && remaining <= v) { sel_bin = (unsigned)t; sel_off = vex; }
      __syncthreads();
      prefix |= sel_bin << shift;
      remaining -= sel_off;
    }
#pragma unroll
    for (int i = 0; i < 16; ++i) {
      int p = t + (i << 8);
      if (key[i] < prefix) {
        unsigned pos = atomicAdd(&cnt1, 1u);
        idxout[q * KNN + pos] = p;
      } else if (key[i] == prefix) {
        unsigned e = atomicAdd(&eqcnt, 1u);
        if (e < 128u) eqbuf[e] = p;
      }
    }
    __syncthreads();
    if (t == 0) {
      int n = (int)min(eqcnt, 128u);
      for (int a = 1; a < n; ++a) {
        int x = eqbuf[a], bi = a - 1;
        while (bi >= 0 && eqbuf[bi] > x) { eqbuf[bi + 1] = eqbuf[bi]; --bi; }
        eqbuf[bi + 1] = x;
      }
      int base = (int)cnt1;
      for (int j = 0; j < (int)remaining; ++j) idxout[q * KNN + base + j] = eqbuf[j];
    }
  }
}

// ---------- layer1 MFMA: gather bf16 -> y1 = W1 g + b1; stats partials; y1 bf16 ----------
__global__ __launch_bounds__(256) void k_mlp1(const unsigned short* __restrict__ ptsTbf,
                                              const float* __restrict__ xyz,
                                              const float* __restrict__ nxyz,
                                              const int* __restrict__ idx,
                                              const unsigned short* __restrict__ w1f,
                                              const float* __restrict__ b1,
                                              unsigned short* __restrict__ y1,
                                              float* __restrict__ part1) {
  __shared__ unsigned short zs[64 * 128];   // A-tile (swz ^(row&7)<<4), then y1-T (swz ^(row&3)<<6)
  int t = threadIdx.x;
  int m0 = blockIdx.x * 64;
  int b = m0 >> 15;
  int lane = t & 63, w = t >> 6;
  bf16x8 bfrag[2][3];
  {
    const uint4* wp = reinterpret_cast<const uint4*>(w1f);
#pragma unroll
    for (int nt = 0; nt < 2; ++nt)
#pragma unroll
      for (int ks = 0; ks < 3; ++ks)
        bfrag[nt][ks] = __builtin_bit_cast(bf16x8, wp[((w * 2 + nt) * 3 + ks) * 64 + lane]);
  }
  {
    int j = t >> 2, part = t & 3;
    int m = m0 + j;
    int pid = idx[m];
    const uint4* src =
        reinterpret_cast<const uint4*>(ptsTbf + ((size_t)b * Nn + pid) * Cc + part * 16);
    char* zc = reinterpret_cast<char*>(zs);
    int base = j * 256, swz = (j & 7) << 4;
    uint4 s0 = src[0], s1 = src[1];
    *reinterpret_cast<uint4*>(zc + ((base + part * 32) ^ swz)) = s0;
    *reinterpret_cast<uint4*>(zc + ((base + part * 32 + 16) ^ swz)) = s1;
    uint4 ex = make_uint4(0u, 0u, 0u, 0u);
    if (part == 0) {
      const float* xp = xyz + ((size_t)b * Nn + pid) * 3;
      int s = (m >> 5) & (Sn - 1);
      const float* qp = nxyz + (size_t)(b * Sn + s) * 3;
      ex.x = (unsigned)f2bf(xp[0]) | ((unsigned)f2bf(xp[1]) << 16);
      ex.y = (unsigned)f2bf(xp[2]) | ((unsigned)f2bf(qp[0]) << 16);
      ex.z = (unsigned)f2bf(qp[1]) | ((unsigned)f2bf(qp[2]) << 16);
    }
    *reinterpret_cast<uint4*>(zc + ((base + (8 + part) * 16) ^ swz)) = ex;
  }
  __syncthreads();
  f32x4 acc[4][2];
#pragma unroll
  for (int mt = 0; mt < 4; ++mt)
#pragma unroll
    for (int nt = 0; nt < 2; ++nt) acc[mt][nt] = f32x4{0.f, 0.f, 0.f, 0.f};
  int r15 = lane & 15, rhi = lane >> 4;
  const char* zc = reinterpret_cast<const char*>(zs);
#pragma unroll
  for (int mt = 0; mt < 4; ++mt) {
    int row = mt * 16 + r15;
    bf16x8 af[3];
#pragma unroll
    for (int ks = 0; ks < 3; ++ks)
      af[ks] = __builtin_bit_cast(
          bf16x8, *reinterpret_cast<const uint4*>(
                      zc + ((row * 256 + ks * 64 + rhi * 16) ^ ((row & 7) << 4))));
#pragma unroll
    for (int nt = 0; nt < 2; ++nt)
#pragma unroll
      for (int ks = 0; ks < 3; ++ks)
        acc[mt][nt] =
            __builtin_amdgcn_mfma_f32_16x16x32_bf16(af[ks], bfrag[nt][ks], acc[mt][nt], 0, 0, 0);
  }
  __syncthreads();
  char* zcw = reinterpret_cast<char*>(zs);
#pragma unroll
  for (int nt = 0; nt < 2; ++nt) {
    int col = w * 32 + nt * 16 + r15;
    float bv = b1[col];
    float s = 0.f, ss = 0.f;
#pragma unroll
    for (int mt = 0; mt < 4; ++mt)
#pragma unroll
      for (int rg = 0; rg < 4; ++rg) {
        float v = acc[mt][nt][rg] + bv;
        s += v; ss += v * v;
        int row = mt * 16 + rhi * 4 + rg;
        *reinterpret_cast<unsigned short*>(zcw + ((row * 256 + col * 2) ^ ((row & 3) << 6))) =
            f2bf(v);
      }
    s += __shfl_xor(s, 16); s += __shfl_xor(s, 32);
    ss += __shfl_xor(ss, 16); ss += __shfl_xor(ss, 32);
    if (lane < 16) {
      part1[(size_t)blockIdx.x * 256 + col] = s;
      part1[(size_t)blockIdx.x * 256 + 128 + col] = ss;
    }
  }
  __syncthreads();
#pragma unroll
  for (int i = 0; i < 4; ++i) {
    int chunk = t + i * 256;
    int row = chunk >> 4, kc = chunk & 15;
    uint4 v = *reinterpret_cast<const uint4*>(
        zc + ((row * 256 + kc * 16) ^ ((row & 3) << 6)));
    *reinterpret_cast<uint4*>(y1 + (size_t)(m0 + row) * C1 + kc * 8) = v;
  }
}

// ---------- stats reduce (layer1) ----------
__global__ __launch_bounds__(256) void k_red1a(const float* __restrict__ part1,
                                               float* __restrict__ p1b) {
  int t = threadIdx.x, r = blockIdx.x;       // 128 blocks x 32 rows
  float acc = 0.f;
  for (int row = r * 32; row < r * 32 + 32; ++row)
    acc += part1[(size_t)row * 256 + t];
  p1b[r * 256 + t] = acc;
}
__global__ __launch_bounds__(256) void k_red1b(const float* __restrict__ p1b,
                                               const float* __restrict__ g1,
                                               const float* __restrict__ be1,
                                               float* __restrict__ bn1) {
  __shared__ float lds[256];
  int t = threadIdx.x;
  float acc = 0.f;
  for (int row = 0; row < 128; ++row) acc += p1b[row * 256 + t];
  lds[t] = acc;
  __syncthreads();
  if (t < 128) {
    float sum = lds[t], ss = lds[128 + t];
    float mean = sum / (float)Mm;
    float var = ss / (float)Mm - mean * mean;
    float a = g1[t] * rsqrtf(var + BNEPS);
    bn1[t] = a;
    bn1[128 + t] = be1[t] - mean * a;
  }
}

// ---------- layer2 MFMA: z1=BNrelu(y1) bf16 -> y2 = W2 z1 + b2 (in acc) ----------
template <int OUTP>
__global__ __launch_bounds__(256) void k_m2(const unsigned short* __restrict__ y1,
                                            const float* __restrict__ bn1c,
                                            const unsigned short* __restrict__ w2f,
                                            const float* __restrict__ b2,
                                            float* __restrict__ part2,
                                            const float* __restrict__ bn2c,
                                            float* __restrict__ out) {
  __shared__ unsigned short zs[64 * 128];   // XOR-swizzled, byte ^= (row&7)<<4
  __shared__ float bns[256];
  int t = threadIdx.x;
  int m0 = blockIdx.x * 64;
  bns[t] = bn1c[t];
  uint4 yv[4];
  const uint4* ybase = reinterpret_cast<const uint4*>(y1 + (size_t)m0 * C1);
#pragma unroll
  for (int i = 0; i < 4; ++i) yv[i] = ybase[t + i * 256];
  int lane = t & 63, w = t >> 6;
  bf16x8 bfrag[4][4];
  {
    const uint4* wp = reinterpret_cast<const uint4*>(w2f) + (size_t)(w * 4) * 4 * 64 + lane;
#pragma unroll
    for (int nt = 0; nt < 4; ++nt)
#pragma unroll
      for (int ks = 0; ks < 4; ++ks)
        bfrag[nt][ks] = __builtin_bit_cast(bf16x8, wp[(nt * 4 + ks) * 64]);
  }
  __syncthreads();   // bns ready
#pragma unroll
  for (int i = 0; i < 4; ++i) {
    int chunk = t + i * 256;
    int row = chunk >> 4, kc = chunk & 15;
    unsigned arr[4] = {yv[i].x, yv[i].y, yv[i].z, yv[i].w};
    unsigned zo[4];
#pragma unroll
    for (int e = 0; e < 4; ++e) {
      int c = kc * 8 + e * 2;
      float lo = __uint_as_float(arr[e] << 16);
      float hi = __uint_as_float(arr[e] & 0xFFFF0000u);
      float z0 = fmaxf(0.f, bns[c] * lo + bns[128 + c]);
      float z1 = fmaxf(0.f, bns[c + 1] * hi + bns[128 + c + 1]);
      zo[e] = (unsigned)f2bf(z0) | ((unsigned)f2bf(z1) << 16);
    }
    int byte = (row * 256 + kc * 16) ^ ((row & 7) << 4);
    *reinterpret_cast<uint4*>(reinterpret_cast<char*>(zs) + byte) =
        make_uint4(zo[0], zo[1], zo[2], zo[3]);
  }
  __syncthreads();
  f32x4 acc[4][4];
#pragma unroll
  for (int mt = 0; mt < 4; ++mt)
#pragma unroll
    for (int nt = 0; nt < 4; ++nt) acc[mt][nt] = f32x4{0.f, 0.f, 0.f, 0.f};
  int r15 = lane & 15, rhi = lane >> 4;
#pragma unroll
  for (int mt = 0; mt < 4; ++mt) {
    int row = mt * 16 + r15;
    bf16x8 af[4];
#pragma unroll
    for (int ks = 0; ks < 4; ++ks) {
      int byte = (row * 256 + ks * 64 + rhi * 16) ^ ((row & 7) << 4);
      af[ks] = __builtin_bit_cast(
          bf16x8, *reinterpret_cast<const uint4*>(reinterpret_cast<const char*>(zs) + byte));
    }
#pragma unroll
    for (int nt = 0; nt < 4; ++nt)
#pragma unroll
      for (int ks = 0; ks < 4; ++ks)
        acc[mt][nt] =
            __builtin_amdgcn_mfma_f32_16x16x32_bf16(af[ks], bfrag[nt][ks], acc[mt][nt], 0, 0, 0);
  }
  int wn0 = w * 64;
  if (OUTP == 0) {
#pragma unroll
    for (int nt = 0; nt < 4; ++nt) {
      int col = wn0 + nt * 16 + r15;
      float bv = b2[col];
      float s = 0.f, ss = 0.f;
#pragma unroll
      for (int mt = 0; mt < 4; ++mt)
#pragma unroll
        for (int rg = 0; rg < 4; ++rg) {
          float v = acc[mt][nt][rg] + bv;
          s += v; ss += v * v;
        }
      s += __shfl_xor(s, 16); s += __shfl_xor(s, 32);
      ss += __shfl_xor(ss, 16); ss += __shfl_xor(ss, 32);
      if (lane < 16) {
        part2[(size_t)blockIdx.x * 512 + col] = s;
        part2[(size_t)blockIdx.x * 512 + 256 + col] = ss;
      }
    }
  } else {
    int q0 = m0 >> 5;   // 2 queries per block (32 samples each)
#pragma unroll
    for (int nt = 0; nt < 4; ++nt) {
      int col = wn0 + nt * 16 + r15;
      float bv = b2[col];
      float a2 = bn2c[col], c2 = bn2c[256 + col];
      float mA = -3.0e38f, mB = -3.0e38f;
#pragma unroll
      for (int mt = 0; mt < 4; ++mt)
#pragma unroll
        for (int rg = 0; rg < 4; ++rg) {
          float v = a2 * (acc[mt][nt][rg] + bv) + c2;
          if (mt < 2) mA = fmaxf(mA, v); else mB = fmaxf(mB, v);
        }
      mA = fmaxf(mA, __shfl_xor(mA, 16)); mA = fmaxf(mA, __shfl_xor(mA, 32));
      mB = fmaxf(mB, __shfl_xor(mB, 16)); mB = fmaxf(mB, __shfl_xor(mB, 32));
      if (lane < 32) {
        int q = q0 + (lane >> 4);
        float m = (lane < 16) ? mA : mB;
        int b = q >> 10, sIdx = q & (Sn - 1);
        out[OUT_XYZ + ((size_t)(b * C2 + col)) * Sn + sIdx] = fmaxf(0.f, m);
      }
    }
  }
}

// ---------- stats reduce (layer2) ----------
__global__ __launch_bounds__(512) void k_red2a(const float* __restrict__ part2,
                                               float* __restrict__ p2b) {
  int t = threadIdx.x, r = blockIdx.x;       // 128 blocks x 32 rows
  float acc = 0.f;
  for (int row = r * 32; row < r * 32 + 32; ++row)
    acc += part2[(size_t)row * 512 + t];
  p2b[r * 512 + t] = acc;
}
__global__ __launch_bounds__(512) void k_red2b(const float* __restrict__ p2b,
                                               const float* __restrict__ g2,
                                               const float* __restrict__ be2,
                                               float* __restrict__ bn2) {
  __shared__ float lds[512];
  int t = threadIdx.x;
  float acc = 0.f;
  for (int row = 0; row < 128; ++row) acc += p2b[row * 512 + t];
  lds[t] = acc;
  __syncthreads();
  if (t < 256) {
    float sum = lds[t], ss = lds[256 + t];
    float mean = sum / (float)Mm;
    float var = ss / (float)Mm - mean * mean;
    float a = g2[t] * rsqrtf(var + BNEPS);
    bn2[t] = a;
    bn2[256 + t] = be2[t] - mean * a;
  }
}

extern "C" void kernel_launch(void* const* d_in, const int* in_sizes, int n_in,
                              void* d_out, int out_size, void* d_ws, size_t ws_size,
                              hipStream_t stream) {
  (void)in_sizes; (void)n_in; (void)out_size; (void)ws_size;
  const float* xyz  = (const float*)d_in[0];
  const float* pts  = (const float*)d_in[1];
  const float* nxyz = (const float*)d_in[2];
  const float* W1   = (const float*)d_in[3];
  const float* b1   = (const float*)d_in[4];
  const float* g1   = (const float*)d_in[5];
  const float* be1  = (const float*)d_in[6];
  const float* W2   = (const float*)d_in[7];
  const float* b2   = (const float*)d_in[8];
  const float* g2   = (const float*)d_in[9];
  const float* be2  = (const float*)d_in[10];
  float* out = (float*)d_out;
  char* ws = (char*)d_ws;

  int*            idx    = (int*)(ws + OFF_IDX);
  unsigned short* ptsTbf = (unsigned short*)(ws + OFF_PTST);
  float*          part1  = (float*)(ws + OFF_P1);
  float*          part2  = (float*)(ws + OFF_P2);
  float*          p1b    = (float*)(ws + OFF_P1B);
  float*          p2b    = (float*)(ws + OFF_P2B);
  float*          bn1    = (float*)(ws + OFF_BN1);
  float*          bn2    = (float*)(ws + OFF_BN2);
  unsigned short* w2f    = (unsigned short*)(ws + OFF_W2F);
  unsigned short* w1f    = (unsigned short*)(ws + OFF_W1F);
  unsigned short* y1     = (unsigned short*)(ws + OFF_Y1);

  k_prep<<<784, 256, 0, stream>>>(pts, nxyz, W1, W2, ptsTbf, out, w1f, w2f);
  k_knn<<<Qq, 256, 0, stream>>>(xyz, nxyz, idx);
  k_mlp1<<<NB_MLP, 256, 0, stream>>>(ptsTbf, xyz, nxyz, idx, w1f, b1, y1, part1);
  k_red1a<<<128, 256, 0, stream>>>(part1, p1b);
  k_red1b<<<1, 256, 0, stream>>>(p1b, g1, be1, bn1);
  k_m2<0><<<NB_MLP, 256, 0, stream>>>(y1, bn1, w2f, b2, part2, bn2, out);
  k_red2a<<<128, 512, 0, stream>>>(part2, p2b);
  k_red2b<<<1, 512, 0, stream>>>(p2b, g2, be2, bn2);
  k_m2<1><<<NB_MLP, 256, 0, stream>>>(y1, bn1, w2f, b2, part2, bn2, out);
}

// Round 10
// 190.071 us; speedup vs baseline: 1.3662x; 1.3662x over previous
//
#include <hip/hip_runtime.h>
#include <stdint.h>

constexpr int Bn = 8, Nn = 4096, Sn = 1024, Cc = 64, KNN = 32, C1 = 128, C2 = 256;
constexpr int Qq = Bn * Sn;     // 8192 queries
constexpr int Mm = Qq * KNN;    // 262144 samples
constexpr int OUT_XYZ = Bn * Sn * 3;  // 24576 floats (output 0)
constexpr float BNEPS = 1e-5f;
constexpr int CAP = 768;        // kNN candidate buffer
constexpr unsigned RSEL = 16;   // sample order statistic -> E[candidates]=128

// ---------- ws layout ----------
constexpr size_t SZ_IDX  = (size_t)Qq * KNN * 4;        // 1 MB
constexpr size_t SZ_PTST = (size_t)Bn * Nn * Cc * 2;    // 4 MB (bf16)
constexpr int    NB_MLP  = Mm / 64;                     // 4096 blocks
constexpr size_t SZ_P1   = (size_t)NB_MLP * 256 * 4;    // 4 MB
constexpr size_t SZ_P2   = (size_t)NB_MLP * 512 * 4;    // 8 MB
constexpr size_t OFF_IDX  = 0;
constexpr size_t OFF_PTST = OFF_IDX + SZ_IDX;
constexpr size_t OFF_P1   = OFF_PTST + SZ_PTST;
constexpr size_t OFF_P2   = OFF_P1 + SZ_P1;
constexpr size_t OFF_P1B  = OFF_P2 + SZ_P2;
constexpr size_t OFF_P2B  = OFF_P1B + (size_t)128 * 256 * 4;
constexpr size_t OFF_BN1  = OFF_P2B + (size_t)128 * 512 * 4;
constexpr size_t OFF_BN2  = OFF_BN1 + 1024;
constexpr size_t OFF_W2F  = OFF_BN2 + 2048;                  // 64 KB
constexpr size_t OFF_W1F  = OFF_W2F + (size_t)32768 * 2;     // 24 KB
constexpr size_t OFF_Y1   = (OFF_W1F + (size_t)12288 * 2 + 255) & ~(size_t)255;
constexpr size_t OFF_MMX  = OFF_Y1 + (size_t)Mm * C1 * 2;    // max(y2+b2): 8 MB
constexpr size_t OFF_MMN  = OFF_MMX + (size_t)Qq * C2 * 4;   // min(y2+b2): 8 MB
// total ws need ≈ OFF_MMN + 8 MB ≈ 110 MB (ws provided ≥ 218 MB)

typedef __attribute__((ext_vector_type(8))) __bf16 bf16x8;
typedef __attribute__((ext_vector_type(4))) float f32x4;

__device__ __forceinline__ unsigned short f2bf(float f) {
  unsigned u = __float_as_uint(f);
  u = u + 0x7FFFu + ((u >> 16) & 1u);   // RNE
  return (unsigned short)(u >> 16);
}

// ---------- fused prep: ptsT->bf16 | copy new_xyz | W1 frags | W2 frags ----------
__global__ __launch_bounds__(256) void k_prep(const float* __restrict__ pts,
                                              const float* __restrict__ nxyz,
                                              const float* __restrict__ W1,
                                              const float* __restrict__ W2,
                                              unsigned short* __restrict__ ptsTbf,
                                              float* __restrict__ outdst,
                                              unsigned short* __restrict__ w1f,
                                              unsigned short* __restrict__ w2f) {
  int blk = blockIdx.x, t = threadIdx.x;
  if (blk < 512) {                       // points [B,C,N] f32 -> [B,N,C] bf16
    __shared__ float tile[64][65];
    int b = blk >> 6, n0 = (blk & 63) * 64;
    int cl = t & 63, rw = t >> 6;
#pragma unroll
    for (int i = 0; i < 16; ++i) {
      int c = i * 4 + rw;
      tile[cl][c] = pts[((size_t)b * Cc + c) * Nn + n0 + cl];
    }
    __syncthreads();
#pragma unroll
    for (int i = 0; i < 16; ++i) {
      int nf = i * 4 + rw;
      ptsTbf[((size_t)b * Nn + n0 + nf) * Cc + cl] = f2bf(tile[nf][cl]);
    }
  } else if (blk < 608) {                // copy new_xyz to output 0
    int i = t + (blk - 512) * 256;
    if (i < OUT_XYZ) outdst[i] = nxyz[i];
  } else if (blk < 656) {                // W1 [128,70] -> bf16 B-frags, K pad 96
    int u = t + (blk - 608) * 256;       // 12288 total
    int j = u & 7, lane = (u >> 3) & 63, rest = u >> 9;
    int ks = rest % 3, nt = rest / 3;
    int ch = nt * 16 + (lane & 15);
    int k = ks * 32 + (lane >> 4) * 8 + j;
    w1f[u] = (k < 70) ? f2bf(W1[ch * 70 + k]) : (unsigned short)0;
  } else {                               // W2 [256,128] -> bf16 B-frags
    int u = t + (blk - 656) * 256;       // 32768 total
    int j = u & 7, lane = (u >> 3) & 63, ks = (u >> 9) & 3, ntile = u >> 11;
    int col = ntile * 16 + (lane & 15);
    int k = ks * 32 + (lane >> 4) * 8 + j;
    w2f[u] = f2bf(W2[col * C1 + k]);
  }
}

// ballot-aggregated histogram add: one LDS atomic per distinct bin per wave
__device__ __forceinline__ void agg_hist(unsigned* hist, unsigned bin, bool valid, int lane) {
  bool todo = valid;
  while (true) {
    unsigned long long bm = __ballot(todo);
    if (bm == 0ull) break;
    int first = __ffsll(bm) - 1;
    unsigned b = (unsigned)__shfl((int)bin, first);
    unsigned long long m = __ballot(todo && bin == b);
    if (lane == first) atomicAdd(&hist[b], (unsigned)__popcll(m));
    if (todo && bin == b) todo = false;
  }
}

// ---------- kNN: sample-pruned exact select (round-8 proven version) ----------
// Distance bits replicate the reference evaluation (norms plain mul/add, dot FMA
// chain, (A+B)-2*dot) under `fp contract(off)`. Threshold U heuristic; fast path
// only if cnt>=K (superset proof); exact u64 (key<<32|idx) rank reproduces top_k
// tie-break. Fallback: full radix.
__global__ __launch_bounds__(256) void k_knn(const float* __restrict__ xyz,
                                             const float* __restrict__ nxyz,
                                             int* __restrict__ idxout) {
  int q = blockIdx.x, b = q >> 10, t = threadIdx.x;
  int lane = t & 63, w = t >> 6;
  const float* xb = xyz + (size_t)b * Nn * 3;
  float qx = nxyz[q * 3 + 0], qy = nxyz[q * 3 + 1], qz = nxyz[q * 3 + 2];
  unsigned key[16];
  {
#pragma clang fp contract(off)
    float sqq = (qx * qx + qy * qy) + qz * qz;
#pragma unroll
    for (int i = 0; i < 16; ++i) {
      int p = t + (i << 8);
      float xl = xb[p * 3 + 0], yl = xb[p * 3 + 1], zl = xb[p * 3 + 2];
      float sqp = (xl * xl + yl * yl) + zl * zl;
      float dot = __builtin_fmaf(qz, zl, __builtin_fmaf(qy, yl, qx * xl));
      float d = (sqq + sqp) - 2.0f * dot;
      unsigned u = __float_as_uint(d);
      key[i] = (u & 0x80000000u) ? ~u : (u | 0x80000000u);   // monotone map
    }
  }
  __shared__ unsigned long long buf64[CAP];
  __shared__ unsigned hist[256];
  __shared__ unsigned hist2[256];
  __shared__ unsigned wsum[4];
  __shared__ unsigned sel_bin, sel_off, cnt, ovf, thrU;
  __shared__ unsigned eqcnt;
  __shared__ int eqbuf[128];

  unsigned s0 = key[0], s1 = key[8];   // samples: points t and t+2048
  hist[t] = 0;
  hist2[t] = 0;
  if (t == 0) { cnt = 0; ovf = 0; thrU = 0xFFFFFFFFu; }
  __syncthreads();
  // S1: top byte of samples
  agg_hist(hist, s0 >> 24, true, lane);
  agg_hist(hist, s1 >> 24, true, lane);
  __syncthreads();
  {
    unsigned h = hist[t], v = h;
#pragma unroll
    for (int off = 1; off < 64; off <<= 1) {
      unsigned o = __shfl_up(v, off);
      if (lane >= off) v += o;
    }
    if (lane == 63) wsum[w] = v;
    __syncthreads();
    unsigned woff = 0;
    for (int ww = 0; ww < w; ++ww) woff += wsum[ww];
    v += woff;
    unsigned vex = v - h;
    if (vex < RSEL && RSEL <= v) { sel_bin = (unsigned)t; sel_off = RSEL - vex; }
    __syncthreads();
  }
  unsigned sbin = sel_bin, srem = sel_off;
  // S2: byte 2 of samples whose top byte == sbin
  agg_hist(hist2, (s0 >> 16) & 255u, (s0 >> 24) == sbin, lane);
  agg_hist(hist2, (s1 >> 16) & 255u, (s1 >> 24) == sbin, lane);
  __syncthreads();
  {
    unsigned h = hist2[t], v = h;
#pragma unroll
    for (int off = 1; off < 64; off <<= 1) {
      unsigned o = __shfl_up(v, off);
      if (lane >= off) v += o;
    }
    if (lane == 63) wsum[w] = v;
    __syncthreads();
    unsigned woff = 0;
    for (int ww = 0; ww < w; ++ww) woff += wsum[ww];
    v += woff;
    unsigned vex = v - h;
    if (vex < srem && srem <= v) {
      unsigned p16 = (sbin << 8) | (unsigned)t;
      thrU = (p16 >= 0xFFFFu) ? 0xFFFFFFFFu : ((p16 + 1u) << 16);
    }
    __syncthreads();
  }
  unsigned U = thrU;
  // compact candidates (key < U), ballot-aggregated
#pragma unroll
  for (int i = 0; i < 16; ++i) {
    bool take = key[i] < U;
    unsigned long long m = __ballot(take);
    if (m == 0ull) continue;
    unsigned base = 0;
    if (lane == 0) base = atomicAdd(&cnt, (unsigned)__popcll(m));
    base = (unsigned)__shfl((int)base, 0);
    if (take) {
      unsigned off = base + (unsigned)__popcll(m & ((1ull << lane) - 1ull));
      if (off < (unsigned)CAP)
        buf64[off] = ((unsigned long long)key[i] << 32) | (unsigned)(t + (i << 8));
      else
        ovf = 1;
    }
  }
  __syncthreads();
  if (!ovf && cnt >= (unsigned)KNN) {
    // exact rank select; candidate broadcast via readlane (VALU), not LDS reads
    int nc = (int)cnt;
    int nchunk = (nc + 63) >> 6;
    if (nc <= 256) {
      unsigned long long my0 = (t < nc) ? buf64[t] : ~0ull;
      int r0 = 0;
      for (int c = 0; c < nchunk; ++c) {
        int ci = c * 64 + lane;
        unsigned long long v = (ci < nc) ? buf64[ci] : ~0ull;
        unsigned vlo = (unsigned)v, vhi = (unsigned)(v >> 32);
#pragma unroll
        for (int i = 0; i < 64; ++i) {
          unsigned olo = __builtin_amdgcn_readlane(vlo, i);
          unsigned ohi = __builtin_amdgcn_readlane(vhi, i);
          unsigned long long o = ((unsigned long long)ohi << 32) | olo;
          r0 += (o < my0);
        }
      }
      if (t < nc && r0 < KNN) idxout[q * KNN + r0] = (int)(unsigned)(my0 & 0xFFFFFFFFull);
    } else {
      unsigned long long my0 = (t < nc) ? buf64[t] : ~0ull;
      unsigned long long my1 = (t + 256 < nc) ? buf64[t + 256] : ~0ull;
      unsigned long long my2 = (t + 512 < nc) ? buf64[t + 512] : ~0ull;
      int r0 = 0, r1 = 0, r2 = 0;
      for (int c = 0; c < nchunk; ++c) {
        int ci = c * 64 + lane;
        unsigned long long v = (ci < nc) ? buf64[ci] : ~0ull;
        unsigned vlo = (unsigned)v, vhi = (unsigned)(v >> 32);
#pragma unroll
        for (int i = 0; i < 64; ++i) {
          unsigned olo = __builtin_amdgcn_readlane(vlo, i);
          unsigned ohi = __builtin_amdgcn_readlane(vhi, i);
          unsigned long long o = ((unsigned long long)ohi << 32) | olo;
          r0 += (o < my0); r1 += (o < my1); r2 += (o < my2);
        }
      }
      if (r0 < KNN) idxout[q * KNN + r0] = (int)(unsigned)(my0 & 0xFFFFFFFFull);
      if (r1 < KNN) idxout[q * KNN + r1] = (int)(unsigned)(my1 & 0xFFFFFFFFull);
      if (r2 < KNN) idxout[q * KNN + r2] = (int)(unsigned)(my2 & 0xFFFFFFFFull);
    }
  } else {
    // fallback: full 4-pass radix (round-4 proven path)
    unsigned prefix = 0, remaining = (unsigned)KNN;
    if (t == 0) { cnt = 0; eqcnt = 0; }
#pragma unroll
    for (int shift = 24; shift >= 0; shift -= 8) {
      hist[t] = 0;
      __syncthreads();
      unsigned himask = (shift == 24) ? 0u : (0xFFFFFFFFu << ((shift + 8) & 31));
#pragma unroll
      for (int i = 0; i < 16; ++i)
        if ((key[i] & himask) == prefix)
          atomicAdd(&hist[(key[i] >> shift) & 255], 1u);
      __syncthreads();
      unsigned h = hist[t], v = h;
#pragma unroll
      for (int off = 1; off < 64; off <<= 1) {
        unsigned o = __shfl_up(v, off);
        if (lane >= off) v += o;
      }
      if (lane == 63) wsum[w] = v;
      __syncthreads();
      unsigned woff = 0;
      for (int ww = 0; ww < w; ++ww) woff += wsum[ww];
      v += woff;
      unsigned vex = v - h;
      if (vex < remaining && remaining <= v) { sel_bin = (unsigned)t; sel_off = vex; }
      __syncthreads();
      prefix |= sel_bin << shift;
      remaining -= sel_off;
    }
#pragma unroll
    for (int i = 0; i < 16; ++i) {
      int p = t + (i << 8);
      if (key[i] < prefix) {
        unsigned pos = atomicAdd(&cnt, 1u);
        idxout[q * KNN + pos] = p;
      } else if (key[i] == prefix) {
        unsigned e = atomicAdd(&eqcnt, 1u);
        if (e < 128u) eqbuf[e] = p;
      }
    }
    __syncthreads();
    if (t == 0) {
      int n = (int)min(eqcnt, 128u);
      for (int a = 1; a < n; ++a) {
        int x = eqbuf[a], bi = a - 1;
        while (bi >= 0 && eqbuf[bi] > x) { eqbuf[bi + 1] = eqbuf[bi]; --bi; }
        eqbuf[bi + 1] = x;
      }
      int base = (int)cnt;
      for (int j = 0; j < (int)remaining; ++j) idxout[q * KNN + base + j] = eqbuf[j];
    }
  }
}

// ---------- layer1 MFMA: gather bf16 -> y1 = W1 g + b1; stats partials; y1 bf16 ----------
__global__ __launch_bounds__(256) void k_mlp1(const unsigned short* __restrict__ ptsTbf,
                                              const float* __restrict__ xyz,
                                              const float* __restrict__ nxyz,
                                              const int* __restrict__ idx,
                                              const unsigned short* __restrict__ w1f,
                                              const float* __restrict__ b1,
                                              unsigned short* __restrict__ y1,
                                              float* __restrict__ part1) {
  __shared__ unsigned short zs[64 * 128];   // A-tile (swz ^(row&7)<<4), then y1-T (swz ^(row&3)<<6)
  int t = threadIdx.x;
  int m0 = blockIdx.x * 64;
  int b = m0 >> 15;
  int lane = t & 63, w = t >> 6;
  bf16x8 bfrag[2][3];
  {
    const uint4* wp = reinterpret_cast<const uint4*>(w1f);
#pragma unroll
    for (int nt = 0; nt < 2; ++nt)
#pragma unroll
      for (int ks = 0; ks < 3; ++ks)
        bfrag[nt][ks] = __builtin_bit_cast(bf16x8, wp[((w * 2 + nt) * 3 + ks) * 64 + lane]);
  }
  {
    int j = t >> 2, part = t & 3;
    int m = m0 + j;
    int pid = idx[m];
    const uint4* src =
        reinterpret_cast<const uint4*>(ptsTbf + ((size_t)b * Nn + pid) * Cc + part * 16);
    char* zc = reinterpret_cast<char*>(zs);
    int base = j * 256, swz = (j & 7) << 4;
    uint4 s0 = src[0], s1 = src[1];
    *reinterpret_cast<uint4*>(zc + ((base + part * 32) ^ swz)) = s0;
    *reinterpret_cast<uint4*>(zc + ((base + part * 32 + 16) ^ swz)) = s1;
    uint4 ex = make_uint4(0u, 0u, 0u, 0u);
    if (part == 0) {
      const float* xp = xyz + ((size_t)b * Nn + pid) * 3;
      int s = (m >> 5) & (Sn - 1);
      const float* qp = nxyz + (size_t)(b * Sn + s) * 3;
      ex.x = (unsigned)f2bf(xp[0]) | ((unsigned)f2bf(xp[1]) << 16);
      ex.y = (unsigned)f2bf(xp[2]) | ((unsigned)f2bf(qp[0]) << 16);
      ex.z = (unsigned)f2bf(qp[1]) | ((unsigned)f2bf(qp[2]) << 16);
    }
    *reinterpret_cast<uint4*>(zc + ((base + (8 + part) * 16) ^ swz)) = ex;
  }
  __syncthreads();
  f32x4 acc[4][2];
#pragma unroll
  for (int mt = 0; mt < 4; ++mt)
#pragma unroll
    for (int nt = 0; nt < 2; ++nt) acc[mt][nt] = f32x4{0.f, 0.f, 0.f, 0.f};
  int r15 = lane & 15, rhi = lane >> 4;
  const char* zc = reinterpret_cast<const char*>(zs);
#pragma unroll
  for (int mt = 0; mt < 4; ++mt) {
    int row = mt * 16 + r15;
    bf16x8 af[3];
#pragma unroll
    for (int ks = 0; ks < 3; ++ks)
      af[ks] = __builtin_bit_cast(
          bf16x8, *reinterpret_cast<const uint4*>(
                      zc + ((row * 256 + ks * 64 + rhi * 16) ^ ((row & 7) << 4))));
#pragma unroll
    for (int nt = 0; nt < 2; ++nt)
#pragma unroll
      for (int ks = 0; ks < 3; ++ks)
        acc[mt][nt] =
            __builtin_amdgcn_mfma_f32_16x16x32_bf16(af[ks], bfrag[nt][ks], acc[mt][nt], 0, 0, 0);
  }
  __syncthreads();
  char* zcw = reinterpret_cast<char*>(zs);
#pragma unroll
  for (int nt = 0; nt < 2; ++nt) {
    int col = w * 32 + nt * 16 + r15;
    float bv = b1[col];
    float s = 0.f, ss = 0.f;
#pragma unroll
    for (int mt = 0; mt < 4; ++mt)
#pragma unroll
      for (int rg = 0; rg < 4; ++rg) {
        float v = acc[mt][nt][rg] + bv;
        s += v; ss += v * v;
        int row = mt * 16 + rhi * 4 + rg;
        *reinterpret_cast<unsigned short*>(zcw + ((row * 256 + col * 2) ^ ((row & 3) << 6))) =
            f2bf(v);
      }
    s += __shfl_xor(s, 16); s += __shfl_xor(s, 32);
    ss += __shfl_xor(ss, 16); ss += __shfl_xor(ss, 32);
    if (lane < 16) {
      part1[(size_t)blockIdx.x * 256 + col] = s;
      part1[(size_t)blockIdx.x * 256 + 128 + col] = ss;
    }
  }
  __syncthreads();
#pragma unroll
  for (int i = 0; i < 4; ++i) {
    int chunk = t + i * 256;
    int row = chunk >> 4, kc = chunk & 15;
    uint4 v = *reinterpret_cast<const uint4*>(
        zc + ((row * 256 + kc * 16) ^ ((row & 3) << 6)));
    *reinterpret_cast<uint4*>(y1 + (size_t)(m0 + row) * C1 + kc * 8) = v;
  }
}

// ---------- stats reduce (layer1) ----------
__global__ __launch_bounds__(256) void k_red1a(const float* __restrict__ part1,
                                               float* __restrict__ p1b) {
  int t = threadIdx.x, r = blockIdx.x;       // 128 blocks x 32 rows
  float acc = 0.f;
  for (int row = r * 32; row < r * 32 + 32; ++row)
    acc += part1[(size_t)row * 256 + t];
  p1b[r * 256 + t] = acc;
}
__global__ __launch_bounds__(256) void k_red1b(const float* __restrict__ p1b,
                                               const float* __restrict__ g1,
                                               const float* __restrict__ be1,
                                               float* __restrict__ bn1) {
  __shared__ float lds[256];
  int t = threadIdx.x;
  float acc = 0.f;
  for (int row = 0; row < 128; ++row) acc += p1b[row * 256 + t];
  lds[t] = acc;
  __syncthreads();
  if (t < 128) {
    float sum = lds[t], ss = lds[128 + t];
    float mean = sum / (float)Mm;
    float var = ss / (float)Mm - mean * mean;
    float a = g1[t] * rsqrtf(var + BNEPS);
    bn1[t] = a;
    bn1[128 + t] = be1[t] - mean * a;
  }
}

// ---------- layer2 MFMA (single pass): z1=BNrelu(y1) -> y2; stats + per-(q,col) max/min ----------
__global__ __launch_bounds__(256) void k_m2(const unsigned short* __restrict__ y1,
                                            const float* __restrict__ bn1c,
                                            const unsigned short* __restrict__ w2f,
                                            const float* __restrict__ b2,
                                            float* __restrict__ part2,
                                            float* __restrict__ maxv,
                                            float* __restrict__ minv) {
  __shared__ unsigned short zs[64 * 128];   // XOR-swizzled, byte ^= (row&7)<<4
  __shared__ float bns[256];
  int t = threadIdx.x;
  int m0 = blockIdx.x * 64;
  bns[t] = bn1c[t];
  uint4 yv[4];
  const uint4* ybase = reinterpret_cast<const uint4*>(y1 + (size_t)m0 * C1);
#pragma unroll
  for (int i = 0; i < 4; ++i) yv[i] = ybase[t + i * 256];
  int lane = t & 63, w = t >> 6;
  bf16x8 bfrag[4][4];
  {
    const uint4* wp = reinterpret_cast<const uint4*>(w2f) + (size_t)(w * 4) * 4 * 64 + lane;
#pragma unroll
    for (int nt = 0; nt < 4; ++nt)
#pragma unroll
      for (int ks = 0; ks < 4; ++ks)
        bfrag[nt][ks] = __builtin_bit_cast(bf16x8, wp[(nt * 4 + ks) * 64]);
  }
  __syncthreads();   // bns ready
#pragma unroll
  for (int i = 0; i < 4; ++i) {
    int chunk = t + i * 256;
    int row = chunk >> 4, kc = chunk & 15;
    unsigned arr[4] = {yv[i].x, yv[i].y, yv[i].z, yv[i].w};
    unsigned zo[4];
#pragma unroll
    for (int e = 0; e < 4; ++e) {
      int c = kc * 8 + e * 2;
      float lo = __uint_as_float(arr[e] << 16);
      float hi = __uint_as_float(arr[e] & 0xFFFF0000u);
      float z0 = fmaxf(0.f, bns[c] * lo + bns[128 + c]);
      float z1 = fmaxf(0.f, bns[c + 1] * hi + bns[128 + c + 1]);
      zo[e] = (unsigned)f2bf(z0) | ((unsigned)f2bf(z1) << 16);
    }
    int byte = (row * 256 + kc * 16) ^ ((row & 7) << 4);
    *reinterpret_cast<uint4*>(reinterpret_cast<char*>(zs) + byte) =
        make_uint4(zo[0], zo[1], zo[2], zo[3]);
  }
  __syncthreads();
  f32x4 acc[4][4];
#pragma unroll
  for (int mt = 0; mt < 4; ++mt)
#pragma unroll
    for (int nt = 0; nt < 4; ++nt) acc[mt][nt] = f32x4{0.f, 0.f, 0.f, 0.f};
  int r15 = lane & 15, rhi = lane >> 4;
#pragma unroll
  for (int mt = 0; mt < 4; ++mt) {
    int row = mt * 16 + r15;
    bf16x8 af[4];
#pragma unroll
    for (int ks = 0; ks < 4; ++ks) {
      int byte = (row * 256 + ks * 64 + rhi * 16) ^ ((row & 7) << 4);
      af[ks] = __builtin_bit_cast(
          bf16x8, *reinterpret_cast<const uint4*>(reinterpret_cast<const char*>(zs) + byte));
    }
#pragma unroll
    for (int nt = 0; nt < 4; ++nt)
#pragma unroll
      for (int ks = 0; ks < 4; ++ks)
        acc[mt][nt] =
            __builtin_amdgcn_mfma_f32_16x16x32_bf16(af[ks], bfrag[nt][ks], acc[mt][nt], 0, 0, 0);
  }
  int wn0 = w * 64;
  int q0 = m0 >> 5;   // 2 queries per block (32 samples each)
#pragma unroll
  for (int nt = 0; nt < 4; ++nt) {
    int col = wn0 + nt * 16 + r15;
    float bv = b2[col];
    float s = 0.f, ss = 0.f;
    float mA = -3.0e38f, mB = -3.0e38f, nA = 3.0e38f, nB = 3.0e38f;
#pragma unroll
    for (int mt = 0; mt < 4; ++mt)
#pragma unroll
      for (int rg = 0; rg < 4; ++rg) {
        float v = acc[mt][nt][rg] + bv;
        s += v; ss += v * v;
        if (mt < 2) { mA = fmaxf(mA, v); nA = fminf(nA, v); }
        else        { mB = fmaxf(mB, v); nB = fminf(nB, v); }
      }
    s += __shfl_xor(s, 16); s += __shfl_xor(s, 32);
    ss += __shfl_xor(ss, 16); ss += __shfl_xor(ss, 32);
    mA = fmaxf(mA, __shfl_xor(mA, 16)); mA = fmaxf(mA, __shfl_xor(mA, 32));
    mB = fmaxf(mB, __shfl_xor(mB, 16)); mB = fmaxf(mB, __shfl_xor(mB, 32));
    nA = fminf(nA, __shfl_xor(nA, 16)); nA = fminf(nA, __shfl_xor(nA, 32));
    nB = fminf(nB, __shfl_xor(nB, 16)); nB = fminf(nB, __shfl_xor(nB, 32));
    if (lane < 16) {
      part2[(size_t)blockIdx.x * 512 + col] = s;
      part2[(size_t)blockIdx.x * 512 + 256 + col] = ss;
    }
    if (lane < 32) {
      int q = q0 + (lane >> 4);
      float mv = (lane < 16) ? mA : mB;
      float nv = (lane < 16) ? nA : nB;
      maxv[(size_t)q * C2 + col] = mv;
      minv[(size_t)q * C2 + col] = nv;
    }
  }
}

// ---------- stats reduce (layer2) ----------
__global__ __launch_bounds__(512) void k_red2a(const float* __restrict__ part2,
                                               float* __restrict__ p2b) {
  int t = threadIdx.x, r = blockIdx.x;       // 128 blocks x 32 rows
  float acc = 0.f;
  for (int row = r * 32; row < r * 32 + 32; ++row)
    acc += part2[(size_t)row * 512 + t];
  p2b[r * 512 + t] = acc;
}
__global__ __launch_bounds__(512) void k_red2b(const float* __restrict__ p2b,
                                               const float* __restrict__ g2,
                                               const float* __restrict__ be2,
                                               float* __restrict__ bn2) {
  __shared__ float lds[512];
  int t = threadIdx.x;
  float acc = 0.f;
  for (int row = 0; row < 128; ++row) acc += p2b[row * 512 + t];
  lds[t] = acc;
  __syncthreads();
  if (t < 256) {
    float sum = lds[t], ss = lds[256 + t];
    float mean = sum / (float)Mm;
    float var = ss / (float)Mm - mean * mean;
    float a = g2[t] * rsqrtf(var + BNEPS);
    bn2[t] = a;
    bn2[256 + t] = be2[t] - mean * a;
  }
}

// ---------- epilogue: out = relu(a2*(a2>=0 ? max : min) + c2), transposed store ----------
// Monotonicity: relu and x -> a*x+c (per-sign) commute with max over k bit-exactly.
__global__ __launch_bounds__(256) void k_out(const float* __restrict__ maxv,
                                             const float* __restrict__ minv,
                                             const float* __restrict__ bn2,
                                             float* __restrict__ out) {
  __shared__ float tile[64][65];
  int b = blockIdx.z, col0 = blockIdx.y * 64, s0 = blockIdx.x * 64;
  int t = threadIdx.x;
  int chl = t & 63, sr = t >> 6;
  float a = bn2[col0 + chl], c = bn2[256 + col0 + chl];
  bool pos = (a >= 0.0f);
#pragma unroll
  for (int i = 0; i < 16; ++i) {
    int sl = sr * 16 + i;
    size_t q = (size_t)(b * Sn + s0 + sl);
    float v = pos ? maxv[q * C2 + col0 + chl] : minv[q * C2 + col0 + chl];
    tile[chl][sl] = fmaxf(0.f, a * v + c);
  }
  __syncthreads();
  int sl = t & 63, cr = t >> 6;
#pragma unroll
  for (int i = 0; i < 16; ++i) {
    int chl2 = i * 4 + cr;
    out[OUT_XYZ + ((size_t)(b * C2 + col0 + chl2)) * Sn + s0 + sl] = tile[chl2][sl];
  }
}

extern "C" void kernel_launch(void* const* d_in, const int* in_sizes, int n_in,
                              void* d_out, int out_size, void* d_ws, size_t ws_size,
                              hipStream_t stream) {
  (void)in_sizes; (void)n_in; (void)out_size; (void)ws_size;
  const float* xyz  = (const float*)d_in[0];
  const float* pts  = (const float*)d_in[1];
  const float* nxyz = (const float*)d_in[2];
  const float* W1   = (const float*)d_in[3];
  const float* b1   = (const float*)d_in[4];
  const float* g1   = (const float*)d_in[5];
  const float* be1  = (const float*)d_in[6];
  const float* W2   = (const float*)d_in[7];
  const float* b2   = (const float*)d_in[8];
  const float* g2   = (const float*)d_in[9];
  const float* be2  = (const float*)d_in[10];
  float* out = (float*)d_out;
  char* ws = (char*)d_ws;

  int*            idx    = (int*)(ws + OFF_IDX);
  unsigned short* ptsTbf = (unsigned short*)(ws + OFF_PTST);
  float*          part1  = (float*)(ws + OFF_P1);
  float*          part2  = (float*)(ws + OFF_P2);
  float*          p1b    = (float*)(ws + OFF_P1B);
  float*          p2b    = (float*)(ws + OFF_P2B);
  float*          bn1    = (float*)(ws + OFF_BN1);
  float*          bn2    = (float*)(ws + OFF_BN2);
  unsigned short* w2f    = (unsigned short*)(ws + OFF_W2F);
  unsigned short* w1f    = (unsigned short*)(ws + OFF_W1F);
  unsigned short* y1     = (unsigned short*)(ws + OFF_Y1);
  float*          maxv   = (float*)(ws + OFF_MMX);
  float*          minv   = (float*)(ws + OFF_MMN);

  k_prep<<<784, 256, 0, stream>>>(pts, nxyz, W1, W2, ptsTbf, out, w1f, w2f);
  k_knn<<<Qq, 256, 0, stream>>>(xyz, nxyz, idx);
  k_mlp1<<<NB_MLP, 256, 0, stream>>>(ptsTbf, xyz, nxyz, idx, w1f, b1, y1, part1);
  k_red1a<<<128, 256, 0, stream>>>(part1, p1b);
  k_red1b<<<1, 256, 0, stream>>>(p1b, g1, be1, bn1);
  k_m2<<<NB_MLP, 256, 0, stream>>>(y1, bn1, w2f, b2, part2, maxv, minv);
  k_red2a<<<128, 512, 0, stream>>>(part2, p2b);
  k_red2b<<<1, 512, 0, stream>>>(p2b, g2, be2, bn2);
  k_out<<<dim3(Sn / 64, C2 / 64, Bn), 256, 0, stream>>>(maxv, minv, bn2, out);
}

// Round 11
// 153.779 us; speedup vs baseline: 1.6886x; 1.2360x over previous
//
#include <hip/hip_runtime.h>
#include <stdint.h>

constexpr int Bn = 8, Nn = 4096, Sn = 1024, Cc = 64, KNN = 32, C1 = 128, C2 = 256;
constexpr int Qq = Bn * Sn;     // 8192 queries
constexpr int Mm = Qq * KNN;    // 262144 samples
constexpr int OUT_XYZ = Bn * Sn * 3;  // 24576 floats (output 0)
constexpr float BNEPS = 1e-5f;
constexpr unsigned RSEL = 12;   // sample order statistic -> E[candidates]~96

// ---------- ws layout ----------
constexpr size_t SZ_IDX  = (size_t)Qq * KNN * 4;        // 1 MB
constexpr size_t SZ_PTST = (size_t)Bn * Nn * Cc * 2;    // 4 MB (bf16)
constexpr int    NB_MLP  = Mm / 64;                     // 4096 blocks
constexpr size_t SZ_P1   = (size_t)NB_MLP * 256 * 4;    // 4 MB
constexpr size_t SZ_P2   = (size_t)NB_MLP * 512 * 4;    // 8 MB
constexpr size_t OFF_IDX  = 0;
constexpr size_t OFF_PTST = OFF_IDX + SZ_IDX;
constexpr size_t OFF_P1   = OFF_PTST + SZ_PTST;
constexpr size_t OFF_P2   = OFF_P1 + SZ_P1;
constexpr size_t OFF_P1B  = OFF_P2 + SZ_P2;
constexpr size_t OFF_P2B  = OFF_P1B + (size_t)128 * 256 * 4;
constexpr size_t OFF_BN1  = OFF_P2B + (size_t)128 * 512 * 4;
constexpr size_t OFF_BN2  = OFF_BN1 + 1024;
constexpr size_t OFF_W2F  = OFF_BN2 + 2048;                  // 64 KB
constexpr size_t OFF_W1F  = OFF_W2F + (size_t)32768 * 2;     // 24 KB
constexpr size_t OFF_Y1   = (OFF_W1F + (size_t)12288 * 2 + 255) & ~(size_t)255;
constexpr size_t OFF_MMX  = OFF_Y1 + (size_t)Mm * C1 * 2;    // max(y2+b2): 8 MB
constexpr size_t OFF_MMN  = OFF_MMX + (size_t)Qq * C2 * 4;   // min(y2+b2): 8 MB

typedef __attribute__((ext_vector_type(8))) __bf16 bf16x8;
typedef __attribute__((ext_vector_type(4))) float f32x4;

__device__ __forceinline__ unsigned short f2bf(float f) {
  unsigned u = __float_as_uint(f);
  u = u + 0x7FFFu + ((u >> 16) & 1u);   // RNE
  return (unsigned short)(u >> 16);
}

// ballot-aggregated histogram add (use only for CLUSTERED bins, e.g. fp exponent)
__device__ __forceinline__ void agg_hist(unsigned* hist, unsigned bin, bool valid, int lane) {
  bool todo = valid;
  while (true) {
    unsigned long long bm = __ballot(todo);
    if (bm == 0ull) break;
    int first = __ffsll(bm) - 1;
    unsigned b = (unsigned)__shfl((int)bin, first);
    unsigned long long m = __ballot(todo && bin == b);
    if (lane == first) atomicAdd(&hist[b], (unsigned)__popcll(m));
    if (todo && bin == b) todo = false;
  }
}

// ---------- kNN (blocks < Qq) + fused prep (blocks >= Qq) ----------
// Distance bits replicate the reference evaluation (norms plain mul/add, dot FMA
// chain, (A+B)-2*dot) under `fp contract(off)`. Threshold U heuristic; fast path
// only if 32<=cnt<=256 (superset proof). Rank on u32 keys (strict-less); key ties
// detected via rank-histogram -> block-uniform u64 redo (exact top_k tie-break).
// Fallback: full radix (round-4 proven).
__global__ __launch_bounds__(256) void k_knn(const float* __restrict__ xyz,
                                             const float* __restrict__ nxyz,
                                             int* __restrict__ idxout,
                                             const float* __restrict__ pts,
                                             const float* __restrict__ W1,
                                             const float* __restrict__ W2,
                                             unsigned short* __restrict__ ptsTbf,
                                             float* __restrict__ outdst,
                                             unsigned short* __restrict__ w1f,
                                             unsigned short* __restrict__ w2f) {
  int t = threadIdx.x;
  if (blockIdx.x >= (unsigned)Qq) {          // ---- prep branch ----
    int blk = blockIdx.x - Qq;
    if (blk < 512) {                         // points [B,C,N] f32 -> [B,N,C] bf16
      __shared__ float tile[64][65];
      int b = blk >> 6, n0 = (blk & 63) * 64;
      int cl = t & 63, rw = t >> 6;
#pragma unroll
      for (int i = 0; i < 16; ++i) {
        int c = i * 4 + rw;
        tile[cl][c] = pts[((size_t)b * Cc + c) * Nn + n0 + cl];
      }
      __syncthreads();
#pragma unroll
      for (int i = 0; i < 16; ++i) {
        int nf = i * 4 + rw;
        ptsTbf[((size_t)b * Nn + n0 + nf) * Cc + cl] = f2bf(tile[nf][cl]);
      }
    } else if (blk < 608) {                  // copy new_xyz to output 0
      int i = t + (blk - 512) * 256;
      if (i < OUT_XYZ) outdst[i] = nxyz[i];
    } else if (blk < 656) {                  // W1 -> bf16 B-frags, K pad 96
      int u = t + (blk - 608) * 256;
      int j = u & 7, lane = (u >> 3) & 63, rest = u >> 9;
      int ks = rest % 3, nt = rest / 3;
      int ch = nt * 16 + (lane & 15);
      int k = ks * 32 + (lane >> 4) * 8 + j;
      w1f[u] = (k < 70) ? f2bf(W1[ch * 70 + k]) : (unsigned short)0;
    } else {                                 // W2 -> bf16 B-frags
      int u = t + (blk - 656) * 256;
      int j = u & 7, lane = (u >> 3) & 63, ks = (u >> 9) & 3, ntile = u >> 11;
      int col = ntile * 16 + (lane & 15);
      int k = ks * 32 + (lane >> 4) * 8 + j;
      w2f[u] = f2bf(W2[col * C1 + k]);
    }
    return;
  }
  // ---- knn branch ----
  int q = blockIdx.x, b = q >> 10;
  int lane = t & 63, w = t >> 6;
  const float* xb = xyz + (size_t)b * Nn * 3;
  float qx = nxyz[q * 3 + 0], qy = nxyz[q * 3 + 1], qz = nxyz[q * 3 + 2];
  unsigned key[16];
  {
#pragma clang fp contract(off)
    float sqq = (qx * qx + qy * qy) + qz * qz;
#pragma unroll
    for (int i = 0; i < 16; ++i) {
      int p = t + (i << 8);
      float xl = xb[p * 3 + 0], yl = xb[p * 3 + 1], zl = xb[p * 3 + 2];
      float sqp = (xl * xl + yl * yl) + zl * zl;
      float dot = __builtin_fmaf(qz, zl, __builtin_fmaf(qy, yl, qx * xl));
      float d = (sqq + sqp) - 2.0f * dot;
      unsigned u = __float_as_uint(d);
      key[i] = (u & 0x80000000u) ? ~u : (u | 0x80000000u);   // monotone map
    }
  }
  __shared__ unsigned long long buf64[256];
  __shared__ unsigned hist[256];
  __shared__ unsigned hist2[256];
  __shared__ unsigned wsum[4];
  __shared__ unsigned sel_bin, sel_off, cnt, ovf, thrU, tieflag;
  __shared__ unsigned eqcnt;
  __shared__ int eqbuf[128];

  unsigned s0 = key[0], s1 = key[8];   // samples: points t and t+2048
  hist[t] = 0;
  hist2[t] = 0;
  if (t == 0) { cnt = 0; ovf = 0; thrU = 0xFFFFFFFFu; tieflag = 0; }
  __syncthreads();
  // S1: top byte of samples (exponent-clustered -> aggregated adds)
  agg_hist(hist, s0 >> 24, true, lane);
  agg_hist(hist, s1 >> 24, true, lane);
  __syncthreads();
  {
    unsigned h = hist[t], v = h;
#pragma unroll
    for (int off = 1; off < 64; off <<= 1) {
      unsigned o = __shfl_up(v, off);
      if (lane >= off) v += o;
    }
    if (lane == 63) wsum[w] = v;
    __syncthreads();
    unsigned woff = 0;
    for (int ww = 0; ww < w; ++ww) woff += wsum[ww];
    v += woff;
    unsigned vex = v - h;
    if (vex < RSEL && RSEL <= v) { sel_bin = (unsigned)t; sel_off = RSEL - vex; }
    __syncthreads();
  }
  unsigned sbin = sel_bin, srem = sel_off;
  // S2: byte 2 of samples in sbin (uniform bins -> plain atomics, few conflicts)
  if ((s0 >> 24) == sbin) atomicAdd(&hist2[(s0 >> 16) & 255u], 1u);
  if ((s1 >> 24) == sbin) atomicAdd(&hist2[(s1 >> 16) & 255u], 1u);
  __syncthreads();
  {
    unsigned h = hist2[t], v = h;
#pragma unroll
    for (int off = 1; off < 64; off <<= 1) {
      unsigned o = __shfl_up(v, off);
      if (lane >= off) v += o;
    }
    if (lane == 63) wsum[w] = v;
    __syncthreads();
    unsigned woff = 0;
    for (int ww = 0; ww < w; ++ww) woff += wsum[ww];
    v += woff;
    unsigned vex = v - h;
    if (vex < srem && srem <= v) {
      unsigned p16 = (sbin << 8) | (unsigned)t;
      thrU = (p16 >= 0xFFFFu) ? 0xFFFFFFFFu : ((p16 + 1u) << 16);
    }
    __syncthreads();
  }
  unsigned U = thrU;
  // compact candidates (key < U), ballot-aggregated
#pragma unroll
  for (int i = 0; i < 16; ++i) {
    bool take = key[i] < U;
    unsigned long long m = __ballot(take);
    if (m == 0ull) continue;
    unsigned base = 0;
    if (lane == 0) base = atomicAdd(&cnt, (unsigned)__popcll(m));
    base = (unsigned)__shfl((int)base, 0);
    if (take) {
      unsigned off = base + (unsigned)__popcll(m & ((1ull << lane) - 1ull));
      if (off < 256u)
        buf64[off] = ((unsigned long long)key[i] << 32) | (unsigned)(t + (i << 8));
      else
        ovf = 1;
    }
  }
  __syncthreads();
  unsigned ncnt = cnt;
  if (!ovf && ncnt >= (unsigned)KNN && ncnt <= 256u) {
    int nc = (int)ncnt;
    const unsigned* keyhw = reinterpret_cast<const unsigned*>(buf64);  // [2i+1]=key
    bool split = (nc <= 128);
    int cid = split ? (t & 127) : t;
    bool haveC = (cid < nc);
    unsigned mykey = haveC ? keyhw[2 * cid + 1] : 0xFFFFFFFFu;
    int r = 0;
    {
      int c0 = split ? (t >> 7) : 0;
      int c1 = split ? (c0 + 1) : ((nc + 63) >> 6);
      for (int c = c0; c < c1 && c * 64 < nc; ++c) {
        int ci = c * 64 + lane;
        unsigned bk = (ci < nc) ? keyhw[2 * ci + 1] : 0xFFFFFFFFu;
#pragma unroll
        for (int i = 0; i < 64; ++i) {
          unsigned ok = __builtin_amdgcn_readlane(bk, i);
          r += (ok < mykey);
        }
      }
    }
    if (split) {
      hist[t] = (unsigned)r;
      __syncthreads();
      if (t < 128) r = (int)(hist[t] + hist[t + 128]);
    }
    // tie detection: strict-less u32 ranks collide iff keys tie
    hist2[t] = 0;
    __syncthreads();
    bool writer = haveC && (split ? (t < 128) : true);
    if (writer) atomicAdd(&hist2[r], 1u);
    __syncthreads();
    if (hist2[t] > 1u) tieflag = 1;
    __syncthreads();
    if (tieflag) {   // rare: exact u64 redo (block-uniform)
      unsigned long long my64 = haveC ? buf64[cid] : ~0ull;
      int rr = 0;
      int nchunk = (nc + 63) >> 6;
      for (int c = 0; c < nchunk; ++c) {
        int ci = c * 64 + lane;
        unsigned long long v = (ci < nc) ? buf64[ci] : ~0ull;
        unsigned vlo = (unsigned)v, vhi = (unsigned)(v >> 32);
#pragma unroll
        for (int i = 0; i < 64; ++i) {
          unsigned olo = __builtin_amdgcn_readlane(vlo, i);
          unsigned ohi = __builtin_amdgcn_readlane(vhi, i);
          unsigned long long o = ((unsigned long long)ohi << 32) | olo;
          rr += (o < my64);
        }
      }
      r = rr;
    }
    if (writer && r < KNN)
      idxout[q * KNN + r] = (int)(unsigned)(buf64[cid] & 0xFFFFFFFFull);
  } else {
    // fallback: full 4-pass radix (round-4 proven path)
    unsigned prefix = 0, remaining = (unsigned)KNN;
    if (t == 0) { cnt = 0; eqcnt = 0; }
#pragma unroll
    for (int shift = 24; shift >= 0; shift -= 8) {
      hist[t] = 0;
      __syncthreads();
      unsigned himask = (shift == 24) ? 0u : (0xFFFFFFFFu << ((shift + 8) & 31));
#pragma unroll
      for (int i = 0; i < 16; ++i)
        if ((key[i] & himask) == prefix)
          atomicAdd(&hist[(key[i] >> shift) & 255], 1u);
      __syncthreads();
      unsigned h = hist[t], v = h;
#pragma unroll
      for (int off = 1; off < 64; off <<= 1) {
        unsigned o = __shfl_up(v, off);
        if (lane >= off) v += o;
      }
      if (lane == 63) wsum[w] = v;
      __syncthreads();
      unsigned woff = 0;
      for (int ww = 0; ww < w; ++ww) woff += wsum[ww];
      v += woff;
      unsigned vex = v - h;
      if (vex < remaining && remaining <= v) { sel_bin = (unsigned)t; sel_off = vex; }
      __syncthreads();
      prefix |= sel_bin << shift;
      remaining -= sel_off;
    }
#pragma unroll
    for (int i = 0; i < 16; ++i) {
      int p = t + (i << 8);
      if (key[i] < prefix) {
        unsigned pos = atomicAdd(&cnt, 1u);
        idxout[q * KNN + pos] = p;
      } else if (key[i] == prefix) {
        unsigned e = atomicAdd(&eqcnt, 1u);
        if (e < 128u) eqbuf[e] = p;
      }
    }
    __syncthreads();
    if (t == 0) {
      int n = (int)min(eqcnt, 128u);
      for (int a = 1; a < n; ++a) {
        int x = eqbuf[a], bi = a - 1;
        while (bi >= 0 && eqbuf[bi] > x) { eqbuf[bi + 1] = eqbuf[bi]; --bi; }
        eqbuf[bi + 1] = x;
      }
      int base = (int)cnt;
      for (int j = 0; j < (int)remaining; ++j) idxout[q * KNN + base + j] = eqbuf[j];
    }
  }
}

// ---------- layer1 MFMA: gather bf16 -> y1 = W1 g + b1; stats partials; y1 bf16 ----------
__global__ __launch_bounds__(256) void k_mlp1(const unsigned short* __restrict__ ptsTbf,
                                              const float* __restrict__ xyz,
                                              const float* __restrict__ nxyz,
                                              const int* __restrict__ idx,
                                              const unsigned short* __restrict__ w1f,
                                              const float* __restrict__ b1,
                                              unsigned short* __restrict__ y1,
                                              float* __restrict__ part1) {
  __shared__ unsigned short zs[64 * 128];   // A-tile (swz ^(row&7)<<4), then y1-T (swz ^(row&3)<<6)
  int t = threadIdx.x;
  int m0 = blockIdx.x * 64;
  int b = m0 >> 15;
  int lane = t & 63, w = t >> 6;
  bf16x8 bfrag[2][3];
  {
    const uint4* wp = reinterpret_cast<const uint4*>(w1f);
#pragma unroll
    for (int nt = 0; nt < 2; ++nt)
#pragma unroll
      for (int ks = 0; ks < 3; ++ks)
        bfrag[nt][ks] = __builtin_bit_cast(bf16x8, wp[((w * 2 + nt) * 3 + ks) * 64 + lane]);
  }
  {
    int j = t >> 2, part = t & 3;
    int m = m0 + j;
    int pid = idx[m];
    const uint4* src =
        reinterpret_cast<const uint4*>(ptsTbf + ((size_t)b * Nn + pid) * Cc + part * 16);
    char* zc = reinterpret_cast<char*>(zs);
    int base = j * 256, swz = (j & 7) << 4;
    uint4 s0 = src[0], s1 = src[1];
    *reinterpret_cast<uint4*>(zc + ((base + part * 32) ^ swz)) = s0;
    *reinterpret_cast<uint4*>(zc + ((base + part * 32 + 16) ^ swz)) = s1;
    uint4 ex = make_uint4(0u, 0u, 0u, 0u);
    if (part == 0) {
      const float* xp = xyz + ((size_t)b * Nn + pid) * 3;
      int s = (m >> 5) & (Sn - 1);
      const float* qp = nxyz + (size_t)(b * Sn + s) * 3;
      ex.x = (unsigned)f2bf(xp[0]) | ((unsigned)f2bf(xp[1]) << 16);
      ex.y = (unsigned)f2bf(xp[2]) | ((unsigned)f2bf(qp[0]) << 16);
      ex.z = (unsigned)f2bf(qp[1]) | ((unsigned)f2bf(qp[2]) << 16);
    }
    *reinterpret_cast<uint4*>(zc + ((base + (8 + part) * 16) ^ swz)) = ex;
  }
  __syncthreads();
  f32x4 acc[4][2];
#pragma unroll
  for (int mt = 0; mt < 4; ++mt)
#pragma unroll
    for (int nt = 0; nt < 2; ++nt) acc[mt][nt] = f32x4{0.f, 0.f, 0.f, 0.f};
  int r15 = lane & 15, rhi = lane >> 4;
  const char* zc = reinterpret_cast<const char*>(zs);
#pragma unroll
  for (int mt = 0; mt < 4; ++mt) {
    int row = mt * 16 + r15;
    bf16x8 af[3];
#pragma unroll
    for (int ks = 0; ks < 3; ++ks)
      af[ks] = __builtin_bit_cast(
          bf16x8, *reinterpret_cast<const uint4*>(
                      zc + ((row * 256 + ks * 64 + rhi * 16) ^ ((row & 7) << 4))));
#pragma unroll
    for (int nt = 0; nt < 2; ++nt)
#pragma unroll
      for (int ks = 0; ks < 3; ++ks)
        acc[mt][nt] =
            __builtin_amdgcn_mfma_f32_16x16x32_bf16(af[ks], bfrag[nt][ks], acc[mt][nt], 0, 0, 0);
  }
  __syncthreads();
  char* zcw = reinterpret_cast<char*>(zs);
#pragma unroll
  for (int nt = 0; nt < 2; ++nt) {
    int col = w * 32 + nt * 16 + r15;
    float bv = b1[col];
    float s = 0.f, ss = 0.f;
#pragma unroll
    for (int mt = 0; mt < 4; ++mt)
#pragma unroll
      for (int rg = 0; rg < 4; ++rg) {
        float v = acc[mt][nt][rg] + bv;
        s += v; ss += v * v;
        int row = mt * 16 + rhi * 4 + rg;
        *reinterpret_cast<unsigned short*>(zcw + ((row * 256 + col * 2) ^ ((row & 3) << 6))) =
            f2bf(v);
      }
    s += __shfl_xor(s, 16); s += __shfl_xor(s, 32);
    ss += __shfl_xor(ss, 16); ss += __shfl_xor(ss, 32);
    if (lane < 16) {
      part1[(size_t)blockIdx.x * 256 + col] = s;
      part1[(size_t)blockIdx.x * 256 + 128 + col] = ss;
    }
  }
  __syncthreads();
#pragma unroll
  for (int i = 0; i < 4; ++i) {
    int chunk = t + i * 256;
    int row = chunk >> 4, kc = chunk & 15;
    uint4 v = *reinterpret_cast<const uint4*>(
        zc + ((row * 256 + kc * 16) ^ ((row & 3) << 6)));
    *reinterpret_cast<uint4*>(y1 + (size_t)(m0 + row) * C1 + kc * 8) = v;
  }
}

// ---------- stats reduce (layer1) ----------
__global__ __launch_bounds__(256) void k_red1a(const float* __restrict__ part1,
                                               float* __restrict__ p1b) {
  int t = threadIdx.x, r = blockIdx.x;       // 128 blocks x 32 rows
  float acc = 0.f;
  for (int row = r * 32; row < r * 32 + 32; ++row)
    acc += part1[(size_t)row * 256 + t];
  p1b[r * 256 + t] = acc;
}
__global__ __launch_bounds__(256) void k_red1b(const float* __restrict__ p1b,
                                               const float* __restrict__ g1,
                                               const float* __restrict__ be1,
                                               float* __restrict__ bn1) {
  __shared__ float lds[256];
  int t = threadIdx.x;
  float acc = 0.f;
  for (int row = 0; row < 128; ++row) acc += p1b[row * 256 + t];
  lds[t] = acc;
  __syncthreads();
  if (t < 128) {
    float sum = lds[t], ss = lds[128 + t];
    float mean = sum / (float)Mm;
    float var = ss / (float)Mm - mean * mean;
    float a = g1[t] * rsqrtf(var + BNEPS);
    bn1[t] = a;
    bn1[128 + t] = be1[t] - mean * a;
  }
}

// ---------- layer2 MFMA (single pass): z1=BNrelu(y1) -> y2; stats + per-(q,col) max/min ----------
__global__ __launch_bounds__(256) void k_m2(const unsigned short* __restrict__ y1,
                                            const float* __restrict__ bn1c,
                                            const unsigned short* __restrict__ w2f,
                                            const float* __restrict__ b2,
                                            float* __restrict__ part2,
                                            float* __restrict__ maxv,
                                            float* __restrict__ minv) {
  __shared__ unsigned short zs[64 * 128];   // XOR-swizzled, byte ^= (row&7)<<4
  __shared__ float bns[256];
  int t = threadIdx.x;
  int m0 = blockIdx.x * 64;
  bns[t] = bn1c[t];
  uint4 yv[4];
  const uint4* ybase = reinterpret_cast<const uint4*>(y1 + (size_t)m0 * C1);
#pragma unroll
  for (int i = 0; i < 4; ++i) yv[i] = ybase[t + i * 256];
  int lane = t & 63, w = t >> 6;
  bf16x8 bfrag[4][4];
  {
    const uint4* wp = reinterpret_cast<const uint4*>(w2f) + (size_t)(w * 4) * 4 * 64 + lane;
#pragma unroll
    for (int nt = 0; nt < 4; ++nt)
#pragma unroll
      for (int ks = 0; ks < 4; ++ks)
        bfrag[nt][ks] = __builtin_bit_cast(bf16x8, wp[(nt * 4 + ks) * 64]);
  }
  __syncthreads();   // bns ready
#pragma unroll
  for (int i = 0; i < 4; ++i) {
    int chunk = t + i * 256;
    int row = chunk >> 4, kc = chunk & 15;
    unsigned arr[4] = {yv[i].x, yv[i].y, yv[i].z, yv[i].w};
    unsigned zo[4];
#pragma unroll
    for (int e = 0; e < 4; ++e) {
      int c = kc * 8 + e * 2;
      float lo = __uint_as_float(arr[e] << 16);
      float hi = __uint_as_float(arr[e] & 0xFFFF0000u);
      float z0 = fmaxf(0.f, bns[c] * lo + bns[128 + c]);
      float z1 = fmaxf(0.f, bns[c + 1] * hi + bns[128 + c + 1]);
      zo[e] = (unsigned)f2bf(z0) | ((unsigned)f2bf(z1) << 16);
    }
    int byte = (row * 256 + kc * 16) ^ ((row & 7) << 4);
    *reinterpret_cast<uint4*>(reinterpret_cast<char*>(zs) + byte) =
        make_uint4(zo[0], zo[1], zo[2], zo[3]);
  }
  __syncthreads();
  f32x4 acc[4][4];
#pragma unroll
  for (int mt = 0; mt < 4; ++mt)
#pragma unroll
    for (int nt = 0; nt < 4; ++nt) acc[mt][nt] = f32x4{0.f, 0.f, 0.f, 0.f};
  int r15 = lane & 15, rhi = lane >> 4;
#pragma unroll
  for (int mt = 0; mt < 4; ++mt) {
    int row = mt * 16 + r15;
    bf16x8 af[4];
#pragma unroll
    for (int ks = 0; ks < 4; ++ks) {
      int byte = (row * 256 + ks * 64 + rhi * 16) ^ ((row & 7) << 4);
      af[ks] = __builtin_bit_cast(
          bf16x8, *reinterpret_cast<const uint4*>(reinterpret_cast<const char*>(zs) + byte));
    }
#pragma unroll
    for (int nt = 0; nt < 4; ++nt)
#pragma unroll
      for (int ks = 0; ks < 4; ++ks)
        acc[mt][nt] =
            __builtin_amdgcn_mfma_f32_16x16x32_bf16(af[ks], bfrag[nt][ks], acc[mt][nt], 0, 0, 0);
  }
  int wn0 = w * 64;
  int q0 = m0 >> 5;   // 2 queries per block (32 samples each)
#pragma unroll
  for (int nt = 0; nt < 4; ++nt) {
    int col = wn0 + nt * 16 + r15;
    float bv = b2[col];
    float s = 0.f, ss = 0.f;
    float mA = -3.0e38f, mB = -3.0e38f, nA = 3.0e38f, nB = 3.0e38f;
#pragma unroll
    for (int mt = 0; mt < 4; ++mt)
#pragma unroll
      for (int rg = 0; rg < 4; ++rg) {
        float v = acc[mt][nt][rg] + bv;
        s += v; ss += v * v;
        if (mt < 2) { mA = fmaxf(mA, v); nA = fminf(nA, v); }
        else        { mB = fmaxf(mB, v); nB = fminf(nB, v); }
      }
    s += __shfl_xor(s, 16); s += __shfl_xor(s, 32);
    ss += __shfl_xor(ss, 16); ss += __shfl_xor(ss, 32);
    mA = fmaxf(mA, __shfl_xor(mA, 16)); mA = fmaxf(mA, __shfl_xor(mA, 32));
    mB = fmaxf(mB, __shfl_xor(mB, 16)); mB = fmaxf(mB, __shfl_xor(mB, 32));
    nA = fminf(nA, __shfl_xor(nA, 16)); nA = fminf(nA, __shfl_xor(nA, 32));
    nB = fminf(nB, __shfl_xor(nB, 16)); nB = fminf(nB, __shfl_xor(nB, 32));
    if (lane < 16) {
      part2[(size_t)blockIdx.x * 512 + col] = s;
      part2[(size_t)blockIdx.x * 512 + 256 + col] = ss;
    }
    if (lane < 32) {
      int q = q0 + (lane >> 4);
      float mv = (lane < 16) ? mA : mB;
      float nv = (lane < 16) ? nA : nB;
      maxv[(size_t)q * C2 + col] = mv;
      minv[(size_t)q * C2 + col] = nv;
    }
  }
}

// ---------- stats reduce (layer2) ----------
__global__ __launch_bounds__(512) void k_red2a(const float* __restrict__ part2,
                                               float* __restrict__ p2b) {
  int t = threadIdx.x, r = blockIdx.x;       // 128 blocks x 32 rows
  float acc = 0.f;
  for (int row = r * 32; row < r * 32 + 32; ++row)
    acc += part2[(size_t)row * 512 + t];
  p2b[r * 512 + t] = acc;
}
__global__ __launch_bounds__(512) void k_red2b(const float* __restrict__ p2b,
                                               const float* __restrict__ g2,
                                               const float* __restrict__ be2,
                                               float* __restrict__ bn2) {
  __shared__ float lds[512];
  int t = threadIdx.x;
  float acc = 0.f;
  for (int row = 0; row < 128; ++row) acc += p2b[row * 512 + t];
  lds[t] = acc;
  __syncthreads();
  if (t < 256) {
    float sum = lds[t], ss = lds[256 + t];
    float mean = sum / (float)Mm;
    float var = ss / (float)Mm - mean * mean;
    float a = g2[t] * rsqrtf(var + BNEPS);
    bn2[t] = a;
    bn2[256 + t] = be2[t] - mean * a;
  }
}

// ---------- epilogue: out = relu(a2*(a2>=0 ? max : min) + c2), transposed store ----------
// Monotonicity: relu and x -> a*x+c (per-sign) commute with max over k bit-exactly.
__global__ __launch_bounds__(256) void k_out(const float* __restrict__ maxv,
                                             const float* __restrict__ minv,
                                             const float* __restrict__ bn2,
                                             float* __restrict__ out) {
  __shared__ float tile[64][65];
  int b = blockIdx.z, col0 = blockIdx.y * 64, s0 = blockIdx.x * 64;
  int t = threadIdx.x;
  int chl = t & 63, sr = t >> 6;
  float a = bn2[col0 + chl], c = bn2[256 + col0 + chl];
  bool pos = (a >= 0.0f);
#pragma unroll
  for (int i = 0; i < 16; ++i) {
    int sl = sr * 16 + i;
    size_t q = (size_t)(b * Sn + s0 + sl);
    float v = pos ? maxv[q * C2 + col0 + chl] : minv[q * C2 + col0 + chl];
    tile[chl][sl] = fmaxf(0.f, a * v + c);
  }
  __syncthreads();
  int sl = t & 63, cr = t >> 6;
#pragma unroll
  for (int i = 0; i < 16; ++i) {
    int chl2 = i * 4 + cr;
    out[OUT_XYZ + ((size_t)(b * C2 + col0 + chl2)) * Sn + s0 + sl] = tile[chl2][sl];
  }
}

extern "C" void kernel_launch(void* const* d_in, const int* in_sizes, int n_in,
                              void* d_out, int out_size, void* d_ws, size_t ws_size,
                              hipStream_t stream) {
  (void)in_sizes; (void)n_in; (void)out_size; (void)ws_size;
  const float* xyz  = (const float*)d_in[0];
  const float* pts  = (const float*)d_in[1];
  const float* nxyz = (const float*)d_in[2];
  const float* W1   = (const float*)d_in[3];
  const float* b1   = (const float*)d_in[4];
  const float* g1   = (const float*)d_in[5];
  const float* be1  = (const float*)d_in[6];
  const float* W2   = (const float*)d_in[7];
  const float* b2   = (const float*)d_in[8];
  const float* g2   = (const float*)d_in[9];
  const float* be2  = (const float*)d_in[10];
  float* out = (float*)d_out;
  char* ws = (char*)d_ws;

  int*            idx    = (int*)(ws + OFF_IDX);
  unsigned short* ptsTbf = (unsigned short*)(ws + OFF_PTST);
  float*          part1  = (float*)(ws + OFF_P1);
  float*          part2  = (float*)(ws + OFF_P2);
  float*          p1b    = (float*)(ws + OFF_P1B);
  float*          p2b    = (float*)(ws + OFF_P2B);
  float*          bn1    = (float*)(ws + OFF_BN1);
  float*          bn2    = (float*)(ws + OFF_BN2);
  unsigned short* w2f    = (unsigned short*)(ws + OFF_W2F);
  unsigned short* w1f    = (unsigned short*)(ws + OFF_W1F);
  unsigned short* y1     = (unsigned short*)(ws + OFF_Y1);
  float*          maxv   = (float*)(ws + OFF_MMX);
  float*          minv   = (float*)(ws + OFF_MMN);

  k_knn<<<Qq + 784, 256, 0, stream>>>(xyz, nxyz, idx, pts, W1, W2, ptsTbf, out, w1f, w2f);
  k_mlp1<<<NB_MLP, 256, 0, stream>>>(ptsTbf, xyz, nxyz, idx, w1f, b1, y1, part1);
  k_red1a<<<128, 256, 0, stream>>>(part1, p1b);
  k_red1b<<<1, 256, 0, stream>>>(p1b, g1, be1, bn1);
  k_m2<<<NB_MLP, 256, 0, stream>>>(y1, bn1, w2f, b2, part2, maxv, minv);
  k_red2a<<<128, 512, 0, stream>>>(part2, p2b);
  k_red2b<<<1, 512, 0, stream>>>(p2b, g2, be2, bn2);
  k_out<<<dim3(Sn / 64, C2 / 64, Bn), 256, 0, stream>>>(maxv, minv, bn2, out);
}

// Round 14
// 140.933 us; speedup vs baseline: 1.8425x; 1.0912x over previous
//
#include <hip/hip_runtime.h>
#include <stdint.h>

constexpr int Bn = 8, Nn = 4096, Sn = 1024, Cc = 64, KNN = 32, C1 = 128, C2 = 256;
constexpr int Qq = Bn * Sn;     // 8192 queries
constexpr int Mm = Qq * KNN;    // 262144 samples
constexpr int OUT_XYZ = Bn * Sn * 3;  // 24576 floats (output 0)
constexpr float BNEPS = 1e-5f;
constexpr unsigned RSEL = 12;   // sample order statistic -> E[candidates]~96

// ---------- ws layout ----------
constexpr size_t SZ_IDX  = (size_t)Qq * KNN * 4;        // 1 MB
constexpr size_t SZ_PTST = (size_t)Bn * Nn * Cc * 2;    // 4 MB (bf16)
constexpr int    NB_MLP  = Mm / 64;                     // 4096 blocks
constexpr size_t SZ_P1   = (size_t)NB_MLP * 256 * 4;    // 4 MB
constexpr size_t SZ_P2   = (size_t)NB_MLP * 512 * 4;    // 8 MB
constexpr size_t OFF_IDX  = 0;
constexpr size_t OFF_PTST = OFF_IDX + SZ_IDX;
constexpr size_t OFF_P1   = OFF_PTST + SZ_PTST;
constexpr size_t OFF_P2   = OFF_P1 + SZ_P1;
constexpr size_t OFF_P1B  = OFF_P2 + SZ_P2;
constexpr size_t OFF_P2B  = OFF_P1B + (size_t)128 * 256 * 4;
constexpr size_t OFF_BN1  = OFF_P2B + (size_t)128 * 512 * 4;
constexpr size_t OFF_BN2  = OFF_BN1 + 1024;
constexpr size_t OFF_W2F  = OFF_BN2 + 2048;                  // 64 KB
constexpr size_t OFF_W1F  = OFF_W2F + (size_t)32768 * 2;     // 24 KB
constexpr size_t OFF_Y1   = (OFF_W1F + (size_t)12288 * 2 + 255) & ~(size_t)255;
constexpr size_t OFF_VAL  = OFF_Y1 + (size_t)Mm * C1 * 2;    // sign-selected extreme: 8 MB

typedef __attribute__((ext_vector_type(8))) __bf16 bf16x8;
typedef __attribute__((ext_vector_type(4))) float f32x4;

__device__ __forceinline__ unsigned short f2bf(float f) {
  unsigned u = __float_as_uint(f);
  u = u + 0x7FFFu + ((u >> 16) & 1u);   // RNE
  return (unsigned short)(u >> 16);
}

// ballot-aggregated histogram add (use only for CLUSTERED bins, e.g. fp exponent)
__device__ __forceinline__ void agg_hist(unsigned* hist, unsigned bin, bool valid, int lane) {
  bool todo = valid;
  while (true) {
    unsigned long long bm = __ballot(todo);
    if (bm == 0ull) break;
    int first = __ffsll(bm) - 1;
    unsigned b = (unsigned)__shfl((int)bin, first);
    unsigned long long m = __ballot(todo && bin == b);
    if (lane == first) atomicAdd(&hist[b], (unsigned)__popcll(m));
    if (todo && bin == b) todo = false;
  }
}

// ---------- kNN (blocks < Qq) + fused prep (blocks >= Qq; outputs consumed only by LATER kernels) ----------
// Distance bits replicate the reference evaluation (norms plain mul/add, dot FMA
// chain, (A+B)-2*dot) under `fp contract(off)`, computed in-register from
// vectorized float4 loads. Threshold U heuristic; fast path only if 32<=cnt<=256
// (superset proof). Rank on u32 keys; ties -> u64 redo. Fallback: full radix.
__global__ __launch_bounds__(256) void k_knn(const float* __restrict__ xyz,
                                             const float* __restrict__ nxyz,
                                             int* __restrict__ idxout,
                                             const float* __restrict__ pts,
                                             const float* __restrict__ W1,
                                             const float* __restrict__ W2,
                                             unsigned short* __restrict__ ptsTbf,
                                             float* __restrict__ outdst,
                                             unsigned short* __restrict__ w1f,
                                             unsigned short* __restrict__ w2f) {
  int t = threadIdx.x;
  if (blockIdx.x >= (unsigned)Qq) {          // ---- prep branch ----
    int blk = blockIdx.x - Qq;
    if (blk < 512) {                         // points [B,C,N] f32 -> [B,N,C] bf16
      __shared__ float tile[64][65];
      int b = blk >> 6, n0 = (blk & 63) * 64;
      int cl = t & 63, rw = t >> 6;
#pragma unroll
      for (int i = 0; i < 16; ++i) {
        int c = i * 4 + rw;
        tile[cl][c] = pts[((size_t)b * Cc + c) * Nn + n0 + cl];
      }
      __syncthreads();
#pragma unroll
      for (int i = 0; i < 16; ++i) {
        int nf = i * 4 + rw;
        ptsTbf[((size_t)b * Nn + n0 + nf) * Cc + cl] = f2bf(tile[nf][cl]);
      }
    } else if (blk < 608) {                  // copy new_xyz to output 0
      int i = t + (blk - 512) * 256;
      if (i < OUT_XYZ) outdst[i] = nxyz[i];
    } else if (blk < 656) {                  // W1 -> bf16 B-frags, K pad 96
      int u = t + (blk - 608) * 256;
      int j = u & 7, lane = (u >> 3) & 63, rest = u >> 9;
      int ks = rest % 3, nt = rest / 3;
      int ch = nt * 16 + (lane & 15);
      int k = ks * 32 + (lane >> 4) * 8 + j;
      w1f[u] = (k < 70) ? f2bf(W1[ch * 70 + k]) : (unsigned short)0;
    } else {                                 // W2 -> bf16 B-frags
      int u = t + (blk - 656) * 256;
      int j = u & 7, lane = (u >> 3) & 63, ks = (u >> 9) & 3, ntile = u >> 11;
      int col = ntile * 16 + (lane & 15);
      int k = ks * 32 + (lane >> 4) * 8 + j;
      w2f[u] = f2bf(W2[col * C1 + k]);
    }
    return;
  }
  // ---- knn branch ----
  int q = blockIdx.x, b = q >> 10;
  int lane = t & 63, w = t >> 6;
  const float4* xb4 = reinterpret_cast<const float4*>(xyz + (size_t)b * Nn * 3);
  float qx = nxyz[q * 3 + 0], qy = nxyz[q * 3 + 1], qz = nxyz[q * 3 + 2];
  unsigned key[16];
  {
#pragma clang fp contract(off)
    float sqq = (qx * qx + qy * qy) + qz * qz;
#pragma unroll
    for (int h = 0; h < 2; ++h) {            // 2 half-chunks of 8 points
      float fl[24];
#pragma unroll
      for (int j = 0; j < 6; ++j) {
        float4 v = xb4[t * 12 + h * 6 + j];
        fl[4 * j + 0] = v.x; fl[4 * j + 1] = v.y; fl[4 * j + 2] = v.z; fl[4 * j + 3] = v.w;
      }
#pragma unroll
      for (int i = 0; i < 8; ++i) {
        float xl = fl[3 * i], yl = fl[3 * i + 1], zl = fl[3 * i + 2];
        float sqp = (xl * xl + yl * yl) + zl * zl;
        float dot = __builtin_fmaf(qz, zl, __builtin_fmaf(qy, yl, qx * xl));
        float d = (sqq + sqp) - 2.0f * dot;
        unsigned u = __float_as_uint(d);
        key[h * 8 + i] = (u & 0x80000000u) ? ~u : (u | 0x80000000u);   // monotone map
      }
    }
  }
  __shared__ unsigned long long buf64[256];
  __shared__ unsigned hist[256];
  __shared__ unsigned hist2[256];
  __shared__ unsigned wsum[4];
  __shared__ unsigned sel_bin, sel_off, cnt, ovf, thrU, tieflag;
  __shared__ unsigned eqcnt;
  __shared__ int eqbuf[128];

  unsigned s0 = key[0], s1 = key[8];   // samples: points 16t and 16t+8
  hist[t] = 0;
  hist2[t] = 0;
  if (t == 0) { cnt = 0; ovf = 0; thrU = 0xFFFFFFFFu; tieflag = 0; }
  __syncthreads();
  // S1: top byte of samples (exponent-clustered -> aggregated adds)
  agg_hist(hist, s0 >> 24, true, lane);
  agg_hist(hist, s1 >> 24, true, lane);
  __syncthreads();
  {
    unsigned h = hist[t], v = h;
#pragma unroll
    for (int off = 1; off < 64; off <<= 1) {
      unsigned o = __shfl_up(v, off);
      if (lane >= off) v += o;
    }
    if (lane == 63) wsum[w] = v;
    __syncthreads();
    unsigned woff = 0;
    for (int ww = 0; ww < w; ++ww) woff += wsum[ww];
    v += woff;
    unsigned vex = v - h;
    if (vex < RSEL && RSEL <= v) { sel_bin = (unsigned)t; sel_off = RSEL - vex; }
    __syncthreads();
  }
  unsigned sbin = sel_bin, srem = sel_off;
  // S2: byte 2 of samples in sbin (uniform bins -> plain atomics)
  if ((s0 >> 24) == sbin) atomicAdd(&hist2[(s0 >> 16) & 255u], 1u);
  if ((s1 >> 24) == sbin) atomicAdd(&hist2[(s1 >> 16) & 255u], 1u);
  __syncthreads();
  {
    unsigned h = hist2[t], v = h;
#pragma unroll
    for (int off = 1; off < 64; off <<= 1) {
      unsigned o = __shfl_up(v, off);
      if (lane >= off) v += o;
    }
    if (lane == 63) wsum[w] = v;
    __syncthreads();
    unsigned woff = 0;
    for (int ww = 0; ww < w; ++ww) woff += wsum[ww];
    v += woff;
    unsigned vex = v - h;
    if (vex < srem && srem <= v) {
      unsigned p16 = (sbin << 8) | (unsigned)t;
      thrU = (p16 >= 0xFFFFu) ? 0xFFFFFFFFu : ((p16 + 1u) << 16);
    }
    __syncthreads();
  }
  unsigned U = thrU;
  // compact candidates (key < U), ballot-aggregated
#pragma unroll
  for (int i = 0; i < 16; ++i) {
    bool take = key[i] < U;
    unsigned long long m = __ballot(take);
    if (m == 0ull) continue;
    unsigned base = 0;
    if (lane == 0) base = atomicAdd(&cnt, (unsigned)__popcll(m));
    base = (unsigned)__shfl((int)base, 0);
    if (take) {
      unsigned off = base + (unsigned)__popcll(m & ((1ull << lane) - 1ull));
      if (off < 256u)
        buf64[off] = ((unsigned long long)key[i] << 32) | (unsigned)(t * 16 + i);
      else
        ovf = 1;
    }
  }
  __syncthreads();
  unsigned ncnt = cnt;
  if (!ovf && ncnt >= (unsigned)KNN && ncnt <= 256u) {
    int nc = (int)ncnt;
    const unsigned* keyhw = reinterpret_cast<const unsigned*>(buf64);  // [2i+1]=key
    bool split = (nc <= 128);
    int cid = split ? (t & 127) : t;
    bool haveC = (cid < nc);
    unsigned mykey = haveC ? keyhw[2 * cid + 1] : 0xFFFFFFFFu;
    int r = 0;
    {
      int c0 = split ? (t >> 7) : 0;
      int c1 = split ? (c0 + 1) : ((nc + 63) >> 6);
      for (int c = c0; c < c1 && c * 64 < nc; ++c) {
        int ci = c * 64 + lane;
        unsigned bk = (ci < nc) ? keyhw[2 * ci + 1] : 0xFFFFFFFFu;
#pragma unroll
        for (int i = 0; i < 64; ++i) {
          unsigned ok = __builtin_amdgcn_readlane(bk, i);
          r += (ok < mykey);
        }
      }
    }
    if (split) {
      hist[t] = (unsigned)r;
      __syncthreads();
      if (t < 128) r = (int)(hist[t] + hist[t + 128]);
    }
    // tie detection: strict-less u32 ranks collide iff keys tie
    hist2[t] = 0;
    __syncthreads();
    bool writer = haveC && (split ? (t < 128) : true);
    if (writer) atomicAdd(&hist2[r], 1u);
    __syncthreads();
    if (hist2[t] > 1u) tieflag = 1;
    __syncthreads();
    if (tieflag) {   // rare: exact u64 redo (block-uniform)
      unsigned long long my64 = haveC ? buf64[cid] : ~0ull;
      int rr = 0;
      int nchunk = (nc + 63) >> 6;
      for (int c = 0; c < nchunk; ++c) {
        int ci = c * 64 + lane;
        unsigned long long v = (ci < nc) ? buf64[ci] : ~0ull;
        unsigned vlo = (unsigned)v, vhi = (unsigned)(v >> 32);
#pragma unroll
        for (int i = 0; i < 64; ++i) {
          unsigned olo = __builtin_amdgcn_readlane(vlo, i);
          unsigned ohi = __builtin_amdgcn_readlane(vhi, i);
          unsigned long long o = ((unsigned long long)ohi << 32) | olo;
          rr += (o < my64);
        }
      }
      r = rr;
    }
    if (writer && r < KNN)
      idxout[q * KNN + r] = (int)(unsigned)(buf64[cid] & 0xFFFFFFFFull);
  } else {
    // fallback: full 4-pass radix (round-4 proven path)
    unsigned prefix = 0, remaining = (unsigned)KNN;
    if (t == 0) { cnt = 0; eqcnt = 0; }
#pragma unroll
    for (int shift = 24; shift >= 0; shift -= 8) {
      hist[t] = 0;
      __syncthreads();
      unsigned himask = (shift == 24) ? 0u : (0xFFFFFFFFu << ((shift + 8) & 31));
#pragma unroll
      for (int i = 0; i < 16; ++i)
        if ((key[i] & himask) == prefix)
          atomicAdd(&hist[(key[i] >> shift) & 255], 1u);
      __syncthreads();
      unsigned h = hist[t], v = h;
#pragma unroll
      for (int off = 1; off < 64; off <<= 1) {
        unsigned o = __shfl_up(v, off);
        if (lane >= off) v += o;
      }
      if (lane == 63) wsum[w] = v;
      __syncthreads();
      unsigned woff = 0;
      for (int ww = 0; ww < w; ++ww) woff += wsum[ww];
      v += woff;
      unsigned vex = v - h;
      if (vex < remaining && remaining <= v) { sel_bin = (unsigned)t; sel_off = vex; }
      __syncthreads();
      prefix |= sel_bin << shift;
      remaining -= sel_off;
    }
#pragma unroll
    for (int i = 0; i < 16; ++i) {
      int p = t * 16 + i;
      if (key[i] < prefix) {
        unsigned pos = atomicAdd(&cnt, 1u);
        idxout[q * KNN + pos] = p;
      } else if (key[i] == prefix) {
        unsigned e = atomicAdd(&eqcnt, 1u);
        if (e < 128u) eqbuf[e] = p;
      }
    }
    __syncthreads();
    if (t == 0) {
      int n = (int)min(eqcnt, 128u);
      for (int a = 1; a < n; ++a) {
        int x = eqbuf[a], bi = a - 1;
        while (bi >= 0 && eqbuf[bi] > x) { eqbuf[bi + 1] = eqbuf[bi]; --bi; }
        eqbuf[bi + 1] = x;
      }
      int base = (int)cnt;
      for (int j = 0; j < (int)remaining; ++j) idxout[q * KNN + base + j] = eqbuf[j];
    }
  }
}

// ---------- layer1 MFMA: gather bf16 -> y1 = W1 g + b1; stats partials; y1 bf16 ----------
__global__ __launch_bounds__(256) void k_mlp1(const unsigned short* __restrict__ ptsTbf,
                                              const float* __restrict__ xyz,
                                              const float* __restrict__ nxyz,
                                              const int* __restrict__ idx,
                                              const unsigned short* __restrict__ w1f,
                                              const float* __restrict__ b1,
                                              unsigned short* __restrict__ y1,
                                              float* __restrict__ part1) {
  __shared__ unsigned short zs[64 * 128];   // A-tile (swz ^(row&7)<<4), then y1-T (swz ^(row&3)<<6)
  int t = threadIdx.x;
  int m0 = blockIdx.x * 64;
  int b = m0 >> 15;
  int lane = t & 63, w = t >> 6;
  bf16x8 bfrag[2][3];
  {
    const uint4* wp = reinterpret_cast<const uint4*>(w1f);
#pragma unroll
    for (int nt = 0; nt < 2; ++nt)
#pragma unroll
      for (int ks = 0; ks < 3; ++ks)
        bfrag[nt][ks] = __builtin_bit_cast(bf16x8, wp[((w * 2 + nt) * 3 + ks) * 64 + lane]);
  }
  {
    int j = t >> 2, part = t & 3;
    int m = m0 + j;
    int pid = idx[m];
    const uint4* src =
        reinterpret_cast<const uint4*>(ptsTbf + ((size_t)b * Nn + pid) * Cc + part * 16);
    char* zc = reinterpret_cast<char*>(zs);
    int base = j * 256, swz = (j & 7) << 4;
    uint4 s0 = src[0], s1 = src[1];
    *reinterpret_cast<uint4*>(zc + ((base + part * 32) ^ swz)) = s0;
    *reinterpret_cast<uint4*>(zc + ((base + part * 32 + 16) ^ swz)) = s1;
    uint4 ex = make_uint4(0u, 0u, 0u, 0u);
    if (part == 0) {
      const float* xp = xyz + ((size_t)b * Nn + pid) * 3;
      int s = (m >> 5) & (Sn - 1);
      const float* qp = nxyz + (size_t)(b * Sn + s) * 3;
      ex.x = (unsigned)f2bf(xp[0]) | ((unsigned)f2bf(xp[1]) << 16);
      ex.y = (unsigned)f2bf(xp[2]) | ((unsigned)f2bf(qp[0]) << 16);
      ex.z = (unsigned)f2bf(qp[1]) | ((unsigned)f2bf(qp[2]) << 16);
    }
    *reinterpret_cast<uint4*>(zc + ((base + (8 + part) * 16) ^ swz)) = ex;
  }
  __syncthreads();
  f32x4 acc[4][2];
#pragma unroll
  for (int mt = 0; mt < 4; ++mt)
#pragma unroll
    for (int nt = 0; nt < 2; ++nt) acc[mt][nt] = f32x4{0.f, 0.f, 0.f, 0.f};
  int r15 = lane & 15, rhi = lane >> 4;
  const char* zc = reinterpret_cast<const char*>(zs);
#pragma unroll
  for (int mt = 0; mt < 4; ++mt) {
    int row = mt * 16 + r15;
    bf16x8 af[3];
#pragma unroll
    for (int ks = 0; ks < 3; ++ks)
      af[ks] = __builtin_bit_cast(
          bf16x8, *reinterpret_cast<const uint4*>(
                      zc + ((row * 256 + ks * 64 + rhi * 16) ^ ((row & 7) << 4))));
#pragma unroll
    for (int nt = 0; nt < 2; ++nt)
#pragma unroll
      for (int ks = 0; ks < 3; ++ks)
        acc[mt][nt] =
            __builtin_amdgcn_mfma_f32_16x16x32_bf16(af[ks], bfrag[nt][ks], acc[mt][nt], 0, 0, 0);
  }
  __syncthreads();
  char* zcw = reinterpret_cast<char*>(zs);
#pragma unroll
  for (int nt = 0; nt < 2; ++nt) {
    int col = w * 32 + nt * 16 + r15;
    float bv = b1[col];
    float s = 0.f, ss = 0.f;
#pragma unroll
    for (int mt = 0; mt < 4; ++mt)
#pragma unroll
      for (int rg = 0; rg < 4; ++rg) {
        float v = acc[mt][nt][rg] + bv;
        s += v; ss += v * v;
        int row = mt * 16 + rhi * 4 + rg;
        *reinterpret_cast<unsigned short*>(zcw + ((row * 256 + col * 2) ^ ((row & 3) << 6))) =
            f2bf(v);
      }
    s += __shfl_xor(s, 16); s += __shfl_xor(s, 32);
    ss += __shfl_xor(ss, 16); ss += __shfl_xor(ss, 32);
    if (lane < 16) {
      part1[(size_t)blockIdx.x * 256 + col] = s;
      part1[(size_t)blockIdx.x * 256 + 128 + col] = ss;
    }
  }
  __syncthreads();
#pragma unroll
  for (int i = 0; i < 4; ++i) {
    int chunk = t + i * 256;
    int row = chunk >> 4, kc = chunk & 15;
    uint4 v = *reinterpret_cast<const uint4*>(
        zc + ((row * 256 + kc * 16) ^ ((row & 3) << 6)));
    *reinterpret_cast<uint4*>(y1 + (size_t)(m0 + row) * C1 + kc * 8) = v;
  }
}

// ---------- stats reduce (layer1) ----------
__global__ __launch_bounds__(256) void k_red1a(const float* __restrict__ part1,
                                               float* __restrict__ p1b) {
  int t = threadIdx.x, r = blockIdx.x;       // 128 blocks x 32 rows
  float acc = 0.f;
  for (int row = r * 32; row < r * 32 + 32; ++row)
    acc += part1[(size_t)row * 256 + t];
  p1b[r * 256 + t] = acc;
}
__global__ __launch_bounds__(256) void k_red1b(const float* __restrict__ p1b,
                                               const float* __restrict__ g1,
                                               const float* __restrict__ be1,
                                               float* __restrict__ bn1) {
  __shared__ float lds[256];
  int t = threadIdx.x;
  float acc = 0.f;
  for (int row = 0; row < 128; ++row) acc += p1b[row * 256 + t];
  lds[t] = acc;
  __syncthreads();
  if (t < 128) {
    float sum = lds[t], ss = lds[128 + t];
    float mean = sum / (float)Mm;
    float var = ss / (float)Mm - mean * mean;
    float a = g1[t] * rsqrtf(var + BNEPS);
    bn1[t] = a;
    bn1[128 + t] = be1[t] - mean * a;
  }
}

// ---------- layer2 MFMA (single pass): z1=BNrelu(y1) -> y2; stats + g2-sign-selected extreme ----------
__global__ __launch_bounds__(256) void k_m2(const unsigned short* __restrict__ y1,
                                            const float* __restrict__ bn1c,
                                            const unsigned short* __restrict__ w2f,
                                            const float* __restrict__ b2,
                                            const float* __restrict__ g2,
                                            float* __restrict__ part2,
                                            float* __restrict__ valv) {
  __shared__ unsigned short zs[64 * 128];   // XOR-swizzled, byte ^= (row&7)<<4
  __shared__ float bns[256];
  int t = threadIdx.x;
  int m0 = blockIdx.x * 64;
  bns[t] = bn1c[t];
  uint4 yv[4];
  const uint4* ybase = reinterpret_cast<const uint4*>(y1 + (size_t)m0 * C1);
#pragma unroll
  for (int i = 0; i < 4; ++i) yv[i] = ybase[t + i * 256];
  int lane = t & 63, w = t >> 6;
  bf16x8 bfrag[4][4];
  {
    const uint4* wp = reinterpret_cast<const uint4*>(w2f) + (size_t)(w * 4) * 4 * 64 + lane;
#pragma unroll
    for (int nt = 0; nt < 4; ++nt)
#pragma unroll
      for (int ks = 0; ks < 4; ++ks)
        bfrag[nt][ks] = __builtin_bit_cast(bf16x8, wp[(nt * 4 + ks) * 64]);
  }
  __syncthreads();   // bns ready
#pragma unroll
  for (int i = 0; i < 4; ++i) {
    int chunk = t + i * 256;
    int row = chunk >> 4, kc = chunk & 15;
    unsigned arr[4] = {yv[i].x, yv[i].y, yv[i].z, yv[i].w};
    unsigned zo[4];
#pragma unroll
    for (int e = 0; e < 4; ++e) {
      int c = kc * 8 + e * 2;
      float lo = __uint_as_float(arr[e] << 16);
      float hi = __uint_as_float(arr[e] & 0xFFFF0000u);
      float z0 = fmaxf(0.f, bns[c] * lo + bns[128 + c]);
      float z1 = fmaxf(0.f, bns[c + 1] * hi + bns[128 + c + 1]);
      zo[e] = (unsigned)f2bf(z0) | ((unsigned)f2bf(z1) << 16);
    }
    int byte = (row * 256 + kc * 16) ^ ((row & 7) << 4);
    *reinterpret_cast<uint4*>(reinterpret_cast<char*>(zs) + byte) =
        make_uint4(zo[0], zo[1], zo[2], zo[3]);
  }
  __syncthreads();
  f32x4 acc[4][4];
#pragma unroll
  for (int mt = 0; mt < 4; ++mt)
#pragma unroll
    for (int nt = 0; nt < 4; ++nt) acc[mt][nt] = f32x4{0.f, 0.f, 0.f, 0.f};
  int r15 = lane & 15, rhi = lane >> 4;
#pragma unroll
  for (int mt = 0; mt < 4; ++mt) {
    int row = mt * 16 + r15;
    bf16x8 af[4];
#pragma unroll
    for (int ks = 0; ks < 4; ++ks) {
      int byte = (row * 256 + ks * 64 + rhi * 16) ^ ((row & 7) << 4);
      af[ks] = __builtin_bit_cast(
          bf16x8, *reinterpret_cast<const uint4*>(reinterpret_cast<const char*>(zs) + byte));
    }
#pragma unroll
    for (int nt = 0; nt < 4; ++nt)
#pragma unroll
      for (int ks = 0; ks < 4; ++ks)
        acc[mt][nt] =
            __builtin_amdgcn_mfma_f32_16x16x32_bf16(af[ks], bfrag[nt][ks], acc[mt][nt], 0, 0, 0);
  }
  int wn0 = w * 64;
  int q0 = m0 >> 5;   // 2 queries per block (32 samples each)
#pragma unroll
  for (int nt = 0; nt < 4; ++nt) {
    int col = wn0 + nt * 16 + r15;
    float bv = b2[col];
    bool pos = (g2[col] >= 0.0f);   // sign(a2) == sign(g2), rsqrt > 0
    float s = 0.f, ss = 0.f;
    float mA = -3.0e38f, mB = -3.0e38f, nA = 3.0e38f, nB = 3.0e38f;
#pragma unroll
    for (int mt = 0; mt < 4; ++mt)
#pragma unroll
      for (int rg = 0; rg < 4; ++rg) {
        float v = acc[mt][nt][rg] + bv;
        s += v; ss += v * v;
        if (mt < 2) { mA = fmaxf(mA, v); nA = fminf(nA, v); }
        else        { mB = fmaxf(mB, v); nB = fminf(nB, v); }
      }
    float vA = pos ? mA : nA, vB = pos ? mB : nB;
    s += __shfl_xor(s, 16); s += __shfl_xor(s, 32);
    ss += __shfl_xor(ss, 16); ss += __shfl_xor(ss, 32);
    if (pos) {
      vA = fmaxf(vA, __shfl_xor(vA, 16)); vA = fmaxf(vA, __shfl_xor(vA, 32));
      vB = fmaxf(vB, __shfl_xor(vB, 16)); vB = fmaxf(vB, __shfl_xor(vB, 32));
    } else {
      vA = fminf(vA, __shfl_xor(vA, 16)); vA = fminf(vA, __shfl_xor(vA, 32));
      vB = fminf(vB, __shfl_xor(vB, 16)); vB = fminf(vB, __shfl_xor(vB, 32));
    }
    if (lane < 16) {
      part2[(size_t)blockIdx.x * 512 + col] = s;
      part2[(size_t)blockIdx.x * 512 + 256 + col] = ss;
    }
    if (lane < 32) {
      int q = q0 + (lane >> 4);
      valv[(size_t)q * C2 + col] = (lane < 16) ? vA : vB;
    }
  }
}

// ---------- stats reduce (layer2, stage a only) ----------
__global__ __launch_bounds__(512) void k_red2a(const float* __restrict__ part2,
                                               float* __restrict__ p2b) {
  int t = threadIdx.x, r = blockIdx.x;       // 128 blocks x 32 rows
  float acc = 0.f;
  for (int row = r * 32; row < r * 32 + 32; ++row)
    acc += part2[(size_t)row * 512 + t];
  p2b[r * 512 + t] = acc;
}

// ---------- epilogue: derive bn2 slice from p2b; out = relu(a2*val + c2), transposed ----------
// Monotonicity: relu and x -> a*x+c (per sign(a)=sign(g2)) commute with max/min bit-exactly.
__global__ __launch_bounds__(256) void k_out(const float* __restrict__ valv,
                                             const float* __restrict__ p2b,
                                             const float* __restrict__ g2,
                                             const float* __restrict__ be2,
                                             float* __restrict__ out) {
  __shared__ float tile[64][65];
  __shared__ float sred[256], ssred[256];
  __shared__ float as_[64], cs_[64];
  int b = blockIdx.z, col0 = blockIdx.y * 64, s0 = blockIdx.x * 64;
  int t = threadIdx.x;
  int colL = t & 63, grp = t >> 6;
  {
    int col = col0 + colL;
    float s = 0.f, ss = 0.f;
    for (int row = grp * 32; row < grp * 32 + 32; ++row) {
      s += p2b[row * 512 + col];
      ss += p2b[row * 512 + 256 + col];
    }
    sred[grp * 64 + colL] = s;
    ssred[grp * 64 + colL] = ss;
  }
  __syncthreads();
  if (grp == 0) {
    float S = sred[colL] + sred[64 + colL] + sred[128 + colL] + sred[192 + colL];
    float SS = ssred[colL] + ssred[64 + colL] + ssred[128 + colL] + ssred[192 + colL];
    float mean = S / (float)Mm;
    float var = SS / (float)Mm - mean * mean;
    float a = g2[col0 + colL] * rsqrtf(var + BNEPS);
    as_[colL] = a;
    cs_[colL] = be2[col0 + colL] - mean * a;
  }
  __syncthreads();
  float a = as_[colL], c = cs_[colL];
  int sr = grp;
#pragma unroll
  for (int i = 0; i < 16; ++i) {
    int sl = sr * 16 + i;
    size_t q = (size_t)(b * Sn + s0 + sl);
    float v = valv[q * C2 + col0 + colL];
    tile[colL][sl] = fmaxf(0.f, a * v + c);
  }
  __syncthreads();
  int sl = t & 63, cr = t >> 6;
#pragma unroll
  for (int i = 0; i < 16; ++i) {
    int chl2 = i * 4 + cr;
    out[OUT_XYZ + ((size_t)(b * C2 + col0 + chl2)) * Sn + s0 + sl] = tile[chl2][sl];
  }
}

extern "C" void kernel_launch(void* const* d_in, const int* in_sizes, int n_in,
                              void* d_out, int out_size, void* d_ws, size_t ws_size,
                              hipStream_t stream) {
  (void)in_sizes; (void)n_in; (void)out_size; (void)ws_size;
  const float* xyz  = (const float*)d_in[0];
  const float* pts  = (const float*)d_in[1];
  const float* nxyz = (const float*)d_in[2];
  const float* W1   = (const float*)d_in[3];
  const float* b1   = (const float*)d_in[4];
  const float* g1   = (const float*)d_in[5];
  const float* be1  = (const float*)d_in[6];
  const float* W2   = (const float*)d_in[7];
  const float* b2   = (const float*)d_in[8];
  const float* g2   = (const float*)d_in[9];
  const float* be2  = (const float*)d_in[10];
  float* out = (float*)d_out;
  char* ws = (char*)d_ws;

  int*            idx    = (int*)(ws + OFF_IDX);
  unsigned short* ptsTbf = (unsigned short*)(ws + OFF_PTST);
  float*          part1  = (float*)(ws + OFF_P1);
  float*          part2  = (float*)(ws + OFF_P2);
  float*          p1b    = (float*)(ws + OFF_P1B);
  float*          p2b    = (float*)(ws + OFF_P2B);
  float*          bn1    = (float*)(ws + OFF_BN1);
  unsigned short* w2f    = (unsigned short*)(ws + OFF_W2F);
  unsigned short* w1f    = (unsigned short*)(ws + OFF_W1F);
  unsigned short* y1     = (unsigned short*)(ws + OFF_Y1);
  float*          valv   = (float*)(ws + OFF_VAL);

  k_knn<<<Qq + 784, 256, 0, stream>>>(xyz, nxyz, idx, pts, W1, W2, ptsTbf, out, w1f, w2f);
  k_mlp1<<<NB_MLP, 256, 0, stream>>>(ptsTbf, xyz, nxyz, idx, w1f, b1, y1, part1);
  k_red1a<<<128, 256, 0, stream>>>(part1, p1b);
  k_red1b<<<1, 256, 0, stream>>>(p1b, g1, be1, bn1);
  k_m2<<<NB_MLP, 256, 0, stream>>>(y1, bn1, w2f, b2, g2, part2, valv);
  k_red2a<<<128, 512, 0, stream>>>(part2, p2b);
  k_out<<<dim3(Sn / 64, C2 / 64, Bn), 256, 0, stream>>>(valv, p2b, g2, be2, out);
}

// Round 15
// 128.480 us; speedup vs baseline: 2.0211x; 1.0969x over previous
//
#include <hip/hip_runtime.h>
#include <stdint.h>

constexpr int Bn = 8, Nn = 4096, Sn = 1024, Cc = 64, KNN = 32, C1 = 128, C2 = 256;
constexpr int Qq = Bn * Sn;     // 8192 queries
constexpr int Mm = Qq * KNN;    // 262144 samples
constexpr int OUT_XYZ = Bn * Sn * 3;  // 24576 floats (output 0)
constexpr float BNEPS = 1e-5f;
constexpr unsigned RSEL = 12;   // sample order statistic -> E[candidates]~96

// ---------- ws layout ----------
constexpr size_t SZ_IDX  = (size_t)Qq * KNN * 4;        // 1 MB
constexpr size_t SZ_PTST = (size_t)Bn * Nn * Cc * 2;    // 4 MB (bf16)
constexpr int    NB_MLP  = Mm / 64;                     // 4096 blocks
constexpr size_t SZ_P1   = (size_t)NB_MLP * 256 * 4;    // 4 MB
constexpr size_t SZ_P2   = (size_t)NB_MLP * 512 * 4;    // 8 MB
constexpr size_t OFF_IDX  = 0;
constexpr size_t OFF_PTST = OFF_IDX + SZ_IDX;
constexpr size_t OFF_P1   = OFF_PTST + SZ_PTST;
constexpr size_t OFF_P2   = OFF_P1 + SZ_P1;
constexpr size_t OFF_P1B  = OFF_P2 + SZ_P2;
constexpr size_t OFF_P2B  = OFF_P1B + (size_t)128 * 256 * 4;
constexpr size_t OFF_BN1  = OFF_P2B + (size_t)128 * 512 * 4;
constexpr size_t OFF_W2F  = OFF_BN1 + 1024;                  // 64 KB
constexpr size_t OFF_W1F  = OFF_W2F + (size_t)32768 * 2;     // 24 KB
constexpr size_t OFF_VAL  = (OFF_W1F + (size_t)12288 * 2 + 255) & ~(size_t)255;  // extreme: 8 MB

typedef __attribute__((ext_vector_type(8))) __bf16 bf16x8;
typedef __attribute__((ext_vector_type(4))) float f32x4;

__device__ __forceinline__ unsigned short f2bf(float f) {
  unsigned u = __float_as_uint(f);
  u = u + 0x7FFFu + ((u >> 16) & 1u);   // RNE
  return (unsigned short)(u >> 16);
}

// ballot-aggregated histogram add (use only for CLUSTERED bins, e.g. fp exponent)
__device__ __forceinline__ void agg_hist(unsigned* hist, unsigned bin, bool valid, int lane) {
  bool todo = valid;
  while (true) {
    unsigned long long bm = __ballot(todo);
    if (bm == 0ull) break;
    int first = __ffsll(bm) - 1;
    unsigned b = (unsigned)__shfl((int)bin, first);
    unsigned long long m = __ballot(todo && bin == b);
    if (lane == first) atomicAdd(&hist[b], (unsigned)__popcll(m));
    if (todo && bin == b) todo = false;
  }
}

// ---------- kNN (blocks < Qq) + fused prep (blocks >= Qq; outputs consumed only by LATER kernels) ----------
__global__ __launch_bounds__(256) void k_knn(const float* __restrict__ xyz,
                                             const float* __restrict__ nxyz,
                                             int* __restrict__ idxout,
                                             const float* __restrict__ pts,
                                             const float* __restrict__ W1,
                                             const float* __restrict__ W2,
                                             unsigned short* __restrict__ ptsTbf,
                                             float* __restrict__ outdst,
                                             unsigned short* __restrict__ w1f,
                                             unsigned short* __restrict__ w2f) {
  int t = threadIdx.x;
  if (blockIdx.x >= (unsigned)Qq) {          // ---- prep branch ----
    int blk = blockIdx.x - Qq;
    if (blk < 512) {                         // points [B,C,N] f32 -> [B,N,C] bf16
      __shared__ float tile[64][65];
      int b = blk >> 6, n0 = (blk & 63) * 64;
      int cl = t & 63, rw = t >> 6;
#pragma unroll
      for (int i = 0; i < 16; ++i) {
        int c = i * 4 + rw;
        tile[cl][c] = pts[((size_t)b * Cc + c) * Nn + n0 + cl];
      }
      __syncthreads();
#pragma unroll
      for (int i = 0; i < 16; ++i) {
        int nf = i * 4 + rw;
        ptsTbf[((size_t)b * Nn + n0 + nf) * Cc + cl] = f2bf(tile[nf][cl]);
      }
    } else if (blk < 608) {                  // copy new_xyz to output 0
      int i = t + (blk - 512) * 256;
      if (i < OUT_XYZ) outdst[i] = nxyz[i];
    } else if (blk < 656) {                  // W1 -> bf16 B-frags, K pad 96
      int u = t + (blk - 608) * 256;
      int j = u & 7, lane = (u >> 3) & 63, rest = u >> 9;
      int ks = rest % 3, nt = rest / 3;
      int ch = nt * 16 + (lane & 15);
      int k = ks * 32 + (lane >> 4) * 8 + j;
      w1f[u] = (k < 70) ? f2bf(W1[ch * 70 + k]) : (unsigned short)0;
    } else {                                 // W2 -> bf16 B-frags
      int u = t + (blk - 656) * 256;
      int j = u & 7, lane = (u >> 3) & 63, ks = (u >> 9) & 3, ntile = u >> 11;
      int col = ntile * 16 + (lane & 15);
      int k = ks * 32 + (lane >> 4) * 8 + j;
      w2f[u] = f2bf(W2[col * C1 + k]);
    }
    return;
  }
  // ---- knn branch ----
  int q = blockIdx.x, b = q >> 10;
  int lane = t & 63, w = t >> 6;
  const float4* xb4 = reinterpret_cast<const float4*>(xyz + (size_t)b * Nn * 3);
  float qx = nxyz[q * 3 + 0], qy = nxyz[q * 3 + 1], qz = nxyz[q * 3 + 2];
  unsigned key[16];
  {
#pragma clang fp contract(off)
    float sqq = (qx * qx + qy * qy) + qz * qz;
#pragma unroll
    for (int h = 0; h < 2; ++h) {            // 2 half-chunks of 8 points
      float fl[24];
#pragma unroll
      for (int j = 0; j < 6; ++j) {
        float4 v = xb4[t * 12 + h * 6 + j];
        fl[4 * j + 0] = v.x; fl[4 * j + 1] = v.y; fl[4 * j + 2] = v.z; fl[4 * j + 3] = v.w;
      }
#pragma unroll
      for (int i = 0; i < 8; ++i) {
        float xl = fl[3 * i], yl = fl[3 * i + 1], zl = fl[3 * i + 2];
        float sqp = (xl * xl + yl * yl) + zl * zl;
        float dot = __builtin_fmaf(qz, zl, __builtin_fmaf(qy, yl, qx * xl));
        float d = (sqq + sqp) - 2.0f * dot;
        unsigned u = __float_as_uint(d);
        key[h * 8 + i] = (u & 0x80000000u) ? ~u : (u | 0x80000000u);   // monotone map
      }
    }
  }
  __shared__ unsigned long long buf64[256];
  __shared__ unsigned hist[256];
  __shared__ unsigned hist2[256];
  __shared__ unsigned wsum[4];
  __shared__ unsigned sel_bin, sel_off, cnt, ovf, thrU, tieflag;
  __shared__ unsigned eqcnt;
  __shared__ int eqbuf[128];

  unsigned s0 = key[0], s1 = key[8];   // samples: points 16t and 16t+8
  hist[t] = 0;
  hist2[t] = 0;
  if (t == 0) { cnt = 0; ovf = 0; thrU = 0xFFFFFFFFu; tieflag = 0; }
  __syncthreads();
  // S1: top byte of samples (exponent-clustered -> aggregated adds)
  agg_hist(hist, s0 >> 24, true, lane);
  agg_hist(hist, s1 >> 24, true, lane);
  __syncthreads();
  {
    unsigned h = hist[t], v = h;
#pragma unroll
    for (int off = 1; off < 64; off <<= 1) {
      unsigned o = __shfl_up(v, off);
      if (lane >= off) v += o;
    }
    if (lane == 63) wsum[w] = v;
    __syncthreads();
    unsigned woff = 0;
    for (int ww = 0; ww < w; ++ww) woff += wsum[ww];
    v += woff;
    unsigned vex = v - h;
    if (vex < RSEL && RSEL <= v) { sel_bin = (unsigned)t; sel_off = RSEL - vex; }
    __syncthreads();
  }
  unsigned sbin = sel_bin, srem = sel_off;
  // S2: byte 2 of samples in sbin (uniform bins -> plain atomics)
  if ((s0 >> 24) == sbin) atomicAdd(&hist2[(s0 >> 16) & 255u], 1u);
  if ((s1 >> 24) == sbin) atomicAdd(&hist2[(s1 >> 16) & 255u], 1u);
  __syncthreads();
  {
    unsigned h = hist2[t], v = h;
#pragma unroll
    for (int off = 1; off < 64; off <<= 1) {
      unsigned o = __shfl_up(v, off);
      if (lane >= off) v += o;
    }
    if (lane == 63) wsum[w] = v;
    __syncthreads();
    unsigned woff = 0;
    for (int ww = 0; ww < w; ++ww) woff += wsum[ww];
    v += woff;
    unsigned vex = v - h;
    if (vex < srem && srem <= v) {
      unsigned p16 = (sbin << 8) | (unsigned)t;
      thrU = (p16 >= 0xFFFFu) ? 0xFFFFFFFFu : ((p16 + 1u) << 16);
    }
    __syncthreads();
  }
  unsigned U = thrU;
  // compact candidates (key < U), ballot-aggregated
#pragma unroll
  for (int i = 0; i < 16; ++i) {
    bool take = key[i] < U;
    unsigned long long m = __ballot(take);
    if (m == 0ull) continue;
    unsigned base = 0;
    if (lane == 0) base = atomicAdd(&cnt, (unsigned)__popcll(m));
    base = (unsigned)__shfl((int)base, 0);
    if (take) {
      unsigned off = base + (unsigned)__popcll(m & ((1ull << lane) - 1ull));
      if (off < 256u)
        buf64[off] = ((unsigned long long)key[i] << 32) | (unsigned)(t * 16 + i);
      else
        ovf = 1;
    }
  }
  __syncthreads();
  unsigned ncnt = cnt;
  if (!ovf && ncnt >= (unsigned)KNN && ncnt <= 256u) {
    int nc = (int)ncnt;
    const unsigned* keyhw = reinterpret_cast<const unsigned*>(buf64);  // [2i+1]=key
    bool split = (nc <= 128);
    int cid = split ? (t & 127) : t;
    bool haveC = (cid < nc);
    unsigned mykey = haveC ? keyhw[2 * cid + 1] : 0xFFFFFFFFu;
    int r = 0;
    {
      int c0 = split ? (t >> 7) : 0;
      int c1 = split ? (c0 + 1) : ((nc + 63) >> 6);
      for (int c = c0; c < c1 && c * 64 < nc; ++c) {
        int ci = c * 64 + lane;
        unsigned bk = (ci < nc) ? keyhw[2 * ci + 1] : 0xFFFFFFFFu;
#pragma unroll
        for (int i = 0; i < 64; ++i) {
          unsigned ok = __builtin_amdgcn_readlane(bk, i);
          r += (ok < mykey);
        }
      }
    }
    if (split) {
      hist[t] = (unsigned)r;
      __syncthreads();
      if (t < 128) r = (int)(hist[t] + hist[t + 128]);
    }
    // tie detection: strict-less u32 ranks collide iff keys tie
    hist2[t] = 0;
    __syncthreads();
    bool writer = haveC && (split ? (t < 128) : true);
    if (writer) atomicAdd(&hist2[r], 1u);
    __syncthreads();
    if (hist2[t] > 1u) tieflag = 1;
    __syncthreads();
    if (tieflag) {   // rare: exact u64 redo (block-uniform)
      unsigned long long my64 = haveC ? buf64[cid] : ~0ull;
      int rr = 0;
      int nchunk = (nc + 63) >> 6;
      for (int c = 0; c < nchunk; ++c) {
        int ci = c * 64 + lane;
        unsigned long long v = (ci < nc) ? buf64[ci] : ~0ull;
        unsigned vlo = (unsigned)v, vhi = (unsigned)(v >> 32);
#pragma unroll
        for (int i = 0; i < 64; ++i) {
          unsigned olo = __builtin_amdgcn_readlane(vlo, i);
          unsigned ohi = __builtin_amdgcn_readlane(vhi, i);
          unsigned long long o = ((unsigned long long)ohi << 32) | olo;
          rr += (o < my64);
        }
      }
      r = rr;
    }
    if (writer && r < KNN)
      idxout[q * KNN + r] = (int)(unsigned)(buf64[cid] & 0xFFFFFFFFull);
  } else {
    // fallback: full 4-pass radix (round-4 proven path)
    unsigned prefix = 0, remaining = (unsigned)KNN;
    if (t == 0) { cnt = 0; eqcnt = 0; }
#pragma unroll
    for (int shift = 24; shift >= 0; shift -= 8) {
      hist[t] = 0;
      __syncthreads();
      unsigned himask = (shift == 24) ? 0u : (0xFFFFFFFFu << ((shift + 8) & 31));
#pragma unroll
      for (int i = 0; i < 16; ++i)
        if ((key[i] & himask) == prefix)
          atomicAdd(&hist[(key[i] >> shift) & 255], 1u);
      __syncthreads();
      unsigned h = hist[t], v = h;
#pragma unroll
      for (int off = 1; off < 64; off <<= 1) {
        unsigned o = __shfl_up(v, off);
        if (lane >= off) v += o;
      }
      if (lane == 63) wsum[w] = v;
      __syncthreads();
      unsigned woff = 0;
      for (int ww = 0; ww < w; ++ww) woff += wsum[ww];
      v += woff;
      unsigned vex = v - h;
      if (vex < remaining && remaining <= v) { sel_bin = (unsigned)t; sel_off = vex; }
      __syncthreads();
      prefix |= sel_bin << shift;
      remaining -= sel_off;
    }
#pragma unroll
    for (int i = 0; i < 16; ++i) {
      int p = t * 16 + i;
      if (key[i] < prefix) {
        unsigned pos = atomicAdd(&cnt, 1u);
        idxout[q * KNN + pos] = p;
      } else if (key[i] == prefix) {
        unsigned e = atomicAdd(&eqcnt, 1u);
        if (e < 128u) eqbuf[e] = p;
      }
    }
    __syncthreads();
    if (t == 0) {
      int n = (int)min(eqcnt, 128u);
      for (int a = 1; a < n; ++a) {
        int x = eqbuf[a], bi = a - 1;
        while (bi >= 0 && eqbuf[bi] > x) { eqbuf[bi + 1] = eqbuf[bi]; --bi; }
        eqbuf[bi + 1] = x;
      }
      int base = (int)cnt;
      for (int j = 0; j < (int)remaining; ++j) idxout[q * KNN + base + j] = eqbuf[j];
    }
  }
}

// ---------- shared staging helper: gather tile -> zs (swz (j&7)<<4) ----------
__device__ __forceinline__ void stage_gather(unsigned short* zs,
                                             const unsigned short* __restrict__ ptsTbf,
                                             const float* __restrict__ xyz,
                                             const float* __restrict__ nxyz,
                                             const int* __restrict__ idx,
                                             int m0, int b, int t) {
  int j = t >> 2, part = t & 3;
  int m = m0 + j;
  int pid = idx[m];
  const uint4* src =
      reinterpret_cast<const uint4*>(ptsTbf + ((size_t)b * Nn + pid) * Cc + part * 16);
  char* zc = reinterpret_cast<char*>(zs);
  int base = j * 256, swz = (j & 7) << 4;
  uint4 s0 = src[0], s1 = src[1];
  *reinterpret_cast<uint4*>(zc + ((base + part * 32) ^ swz)) = s0;
  *reinterpret_cast<uint4*>(zc + ((base + part * 32 + 16) ^ swz)) = s1;
  uint4 ex = make_uint4(0u, 0u, 0u, 0u);
  if (part == 0) {
    const float* xp = xyz + ((size_t)b * Nn + pid) * 3;
    int s = (m >> 5) & (Sn - 1);
    const float* qp = nxyz + (size_t)(b * Sn + s) * 3;
    ex.x = (unsigned)f2bf(xp[0]) | ((unsigned)f2bf(xp[1]) << 16);
    ex.y = (unsigned)f2bf(xp[2]) | ((unsigned)f2bf(qp[0]) << 16);
    ex.z = (unsigned)f2bf(qp[1]) | ((unsigned)f2bf(qp[2]) << 16);
  }
  *reinterpret_cast<uint4*>(zc + ((base + (8 + part) * 16) ^ swz)) = ex;
}

// ---------- layer1 stats-only: gather + W1 MFMA -> sum/sumsq partials ----------
__global__ __launch_bounds__(256) void k_mlp1s(const unsigned short* __restrict__ ptsTbf,
                                               const float* __restrict__ xyz,
                                               const float* __restrict__ nxyz,
                                               const int* __restrict__ idx,
                                               const unsigned short* __restrict__ w1f,
                                               const float* __restrict__ b1,
                                               float* __restrict__ part1) {
  __shared__ unsigned short zs[64 * 128];
  int t = threadIdx.x;
  int m0 = blockIdx.x * 64;
  int b = m0 >> 15;
  int lane = t & 63, w = t >> 6;
  bf16x8 bfrag[2][3];
  {
    const uint4* wp = reinterpret_cast<const uint4*>(w1f);
#pragma unroll
    for (int nt = 0; nt < 2; ++nt)
#pragma unroll
      for (int ks = 0; ks < 3; ++ks)
        bfrag[nt][ks] = __builtin_bit_cast(bf16x8, wp[((w * 2 + nt) * 3 + ks) * 64 + lane]);
  }
  stage_gather(zs, ptsTbf, xyz, nxyz, idx, m0, b, t);
  __syncthreads();
  f32x4 acc[4][2];
#pragma unroll
  for (int mt = 0; mt < 4; ++mt)
#pragma unroll
    for (int nt = 0; nt < 2; ++nt) acc[mt][nt] = f32x4{0.f, 0.f, 0.f, 0.f};
  int r15 = lane & 15, rhi = lane >> 4;
  const char* zc = reinterpret_cast<const char*>(zs);
#pragma unroll
  for (int mt = 0; mt < 4; ++mt) {
    int row = mt * 16 + r15;
    bf16x8 af[3];
#pragma unroll
    for (int ks = 0; ks < 3; ++ks)
      af[ks] = __builtin_bit_cast(
          bf16x8, *reinterpret_cast<const uint4*>(
                      zc + ((row * 256 + ks * 64 + rhi * 16) ^ ((row & 7) << 4))));
#pragma unroll
    for (int nt = 0; nt < 2; ++nt)
#pragma unroll
      for (int ks = 0; ks < 3; ++ks)
        acc[mt][nt] =
            __builtin_amdgcn_mfma_f32_16x16x32_bf16(af[ks], bfrag[nt][ks], acc[mt][nt], 0, 0, 0);
  }
#pragma unroll
  for (int nt = 0; nt < 2; ++nt) {
    int col = w * 32 + nt * 16 + r15;
    float bv = b1[col];
    float s = 0.f, ss = 0.f;
#pragma unroll
    for (int mt = 0; mt < 4; ++mt)
#pragma unroll
      for (int rg = 0; rg < 4; ++rg) {
        float v = acc[mt][nt][rg] + bv;
        s += v; ss += v * v;
      }
    s += __shfl_xor(s, 16); s += __shfl_xor(s, 32);
    ss += __shfl_xor(ss, 16); ss += __shfl_xor(ss, 32);
    if (lane < 16) {
      part1[(size_t)blockIdx.x * 256 + col] = s;
      part1[(size_t)blockIdx.x * 256 + 128 + col] = ss;
    }
  }
}

// ---------- stats reduce (layer1) ----------
__global__ __launch_bounds__(256) void k_red1a(const float* __restrict__ part1,
                                               float* __restrict__ p1b) {
  int t = threadIdx.x, r = blockIdx.x;       // 128 blocks x 32 rows
  float acc = 0.f;
  for (int row = r * 32; row < r * 32 + 32; ++row)
    acc += part1[(size_t)row * 256 + t];
  p1b[r * 256 + t] = acc;
}
// bn1[t] = a; bn1[128+t] = a*b1 + be1 - mean*a  (b1 folded so fused kernel skips it)
__global__ __launch_bounds__(256) void k_red1b(const float* __restrict__ p1b,
                                               const float* __restrict__ b1,
                                               const float* __restrict__ g1,
                                               const float* __restrict__ be1,
                                               float* __restrict__ bn1) {
  __shared__ float lds[256];
  int t = threadIdx.x;
  float acc = 0.f;
  for (int row = 0; row < 128; ++row) acc += p1b[row * 256 + t];
  lds[t] = acc;
  __syncthreads();
  if (t < 128) {
    float sum = lds[t], ss = lds[128 + t];
    float mean = sum / (float)Mm;
    float var = ss / (float)Mm - mean * mean;
    float a = g1[t] * rsqrtf(var + BNEPS);
    bn1[t] = a;
    bn1[128 + t] = a * b1[t] + (be1[t] - mean * a);
  }
}

// ---------- fused layer1+layer2: gather -> W1 MFMA -> BN1+relu -> W2 MFMA -> stats+extreme ----------
__global__ __launch_bounds__(256) void k_m2f(const unsigned short* __restrict__ ptsTbf,
                                             const float* __restrict__ xyz,
                                             const float* __restrict__ nxyz,
                                             const int* __restrict__ idx,
                                             const unsigned short* __restrict__ w1f,
                                             const float* __restrict__ bn1c,
                                             const unsigned short* __restrict__ w2f,
                                             const float* __restrict__ b2,
                                             const float* __restrict__ g2,
                                             float* __restrict__ part2,
                                             float* __restrict__ valv) {
  __shared__ unsigned short zs[64 * 128];   // gather tile, then z1 tile (both swz (row&7)<<4)
  __shared__ float bns[256];
  int t = threadIdx.x;
  int m0 = blockIdx.x * 64;
  int b = m0 >> 15;
  int lane = t & 63, w = t >> 6;
  bns[t] = bn1c[t];
  bf16x8 b1frag[2][3];
  {
    const uint4* wp = reinterpret_cast<const uint4*>(w1f);
#pragma unroll
    for (int nt = 0; nt < 2; ++nt)
#pragma unroll
      for (int ks = 0; ks < 3; ++ks)
        b1frag[nt][ks] = __builtin_bit_cast(bf16x8, wp[((w * 2 + nt) * 3 + ks) * 64 + lane]);
  }
  stage_gather(zs, ptsTbf, xyz, nxyz, idx, m0, b, t);
  __syncthreads();
  int r15 = lane & 15, rhi = lane >> 4;
  f32x4 acc1[4][2];
#pragma unroll
  for (int mt = 0; mt < 4; ++mt)
#pragma unroll
    for (int nt = 0; nt < 2; ++nt) acc1[mt][nt] = f32x4{0.f, 0.f, 0.f, 0.f};
  {
    const char* zc = reinterpret_cast<const char*>(zs);
#pragma unroll
    for (int mt = 0; mt < 4; ++mt) {
      int row = mt * 16 + r15;
      bf16x8 af[3];
#pragma unroll
      for (int ks = 0; ks < 3; ++ks)
        af[ks] = __builtin_bit_cast(
            bf16x8, *reinterpret_cast<const uint4*>(
                        zc + ((row * 256 + ks * 64 + rhi * 16) ^ ((row & 7) << 4))));
#pragma unroll
      for (int nt = 0; nt < 2; ++nt)
#pragma unroll
        for (int ks = 0; ks < 3; ++ks)
          acc1[mt][nt] = __builtin_amdgcn_mfma_f32_16x16x32_bf16(af[ks], b1frag[nt][ks],
                                                                 acc1[mt][nt], 0, 0, 0);
    }
  }
  __syncthreads();   // gather tile reads done; reuse zs for z1
  {
    char* zcw = reinterpret_cast<char*>(zs);
#pragma unroll
    for (int nt = 0; nt < 2; ++nt) {
      int col = w * 32 + nt * 16 + r15;
      float a = bns[col], c = bns[128 + col];
#pragma unroll
      for (int mt = 0; mt < 4; ++mt)
#pragma unroll
        for (int rg = 0; rg < 4; ++rg) {
          int row = mt * 16 + rhi * 4 + rg;
          float z = fmaxf(0.f, a * acc1[mt][nt][rg] + c);
          *reinterpret_cast<unsigned short*>(
              zcw + ((row * 256 + col * 2) ^ ((row & 7) << 4))) = f2bf(z);
        }
    }
  }
  __syncthreads();
  // W2 fragments (loaded after acc1 is dead to cap VGPR)
  bf16x8 b2frag[4][4];
  {
    const uint4* wp = reinterpret_cast<const uint4*>(w2f) + (size_t)(w * 4) * 4 * 64 + lane;
#pragma unroll
    for (int nt = 0; nt < 4; ++nt)
#pragma unroll
      for (int ks = 0; ks < 4; ++ks)
        b2frag[nt][ks] = __builtin_bit_cast(bf16x8, wp[(nt * 4 + ks) * 64]);
  }
  f32x4 acc[4][4];
#pragma unroll
  for (int mt = 0; mt < 4; ++mt)
#pragma unroll
    for (int nt = 0; nt < 4; ++nt) acc[mt][nt] = f32x4{0.f, 0.f, 0.f, 0.f};
  {
    const char* zc = reinterpret_cast<const char*>(zs);
#pragma unroll
    for (int mt = 0; mt < 4; ++mt) {
      int row = mt * 16 + r15;
      bf16x8 af[4];
#pragma unroll
      for (int ks = 0; ks < 4; ++ks)
        af[ks] = __builtin_bit_cast(
            bf16x8, *reinterpret_cast<const uint4*>(
                        zc + ((row * 256 + ks * 64 + rhi * 16) ^ ((row & 7) << 4))));
#pragma unroll
      for (int nt = 0; nt < 4; ++nt)
#pragma unroll
        for (int ks = 0; ks < 4; ++ks)
          acc[mt][nt] = __builtin_amdgcn_mfma_f32_16x16x32_bf16(af[ks], b2frag[nt][ks],
                                                                acc[mt][nt], 0, 0, 0);
    }
  }
  int wn0 = w * 64;
  int q0 = m0 >> 5;   // 2 queries per block (32 samples each)
#pragma unroll
  for (int nt = 0; nt < 4; ++nt) {
    int col = wn0 + nt * 16 + r15;
    float bv = b2[col];
    bool pos = (g2[col] >= 0.0f);   // sign(a2) == sign(g2), rsqrt > 0
    float s = 0.f, ss = 0.f;
    float mA = -3.0e38f, mB = -3.0e38f, nA = 3.0e38f, nB = 3.0e38f;
#pragma unroll
    for (int mt = 0; mt < 4; ++mt)
#pragma unroll
      for (int rg = 0; rg < 4; ++rg) {
        float v = acc[mt][nt][rg] + bv;
        s += v; ss += v * v;
        if (mt < 2) { mA = fmaxf(mA, v); nA = fminf(nA, v); }
        else        { mB = fmaxf(mB, v); nB = fminf(nB, v); }
      }
    float vA = pos ? mA : nA, vB = pos ? mB : nB;
    s += __shfl_xor(s, 16); s += __shfl_xor(s, 32);
    ss += __shfl_xor(ss, 16); ss += __shfl_xor(ss, 32);
    if (pos) {
      vA = fmaxf(vA, __shfl_xor(vA, 16)); vA = fmaxf(vA, __shfl_xor(vA, 32));
      vB = fmaxf(vB, __shfl_xor(vB, 16)); vB = fmaxf(vB, __shfl_xor(vB, 32));
    } else {
      vA = fminf(vA, __shfl_xor(vA, 16)); vA = fminf(vA, __shfl_xor(vA, 32));
      vB = fminf(vB, __shfl_xor(vB, 16)); vB = fminf(vB, __shfl_xor(vB, 32));
    }
    if (lane < 16) {
      part2[(size_t)blockIdx.x * 512 + col] = s;
      part2[(size_t)blockIdx.x * 512 + 256 + col] = ss;
    }
    if (lane < 32) {
      int q = q0 + (lane >> 4);
      valv[(size_t)q * C2 + col] = (lane < 16) ? vA : vB;
    }
  }
}

// ---------- stats reduce (layer2, stage a only) ----------
__global__ __launch_bounds__(512) void k_red2a(const float* __restrict__ part2,
                                               float* __restrict__ p2b) {
  int t = threadIdx.x, r = blockIdx.x;       // 128 blocks x 32 rows
  float acc = 0.f;
  for (int row = r * 32; row < r * 32 + 32; ++row)
    acc += part2[(size_t)row * 512 + t];
  p2b[r * 512 + t] = acc;
}

// ---------- epilogue: derive bn2 slice from p2b; out = relu(a2*val + c2), transposed ----------
__global__ __launch_bounds__(256) void k_out(const float* __restrict__ valv,
                                             const float* __restrict__ p2b,
                                             const float* __restrict__ g2,
                                             const float* __restrict__ be2,
                                             float* __restrict__ out) {
  __shared__ float tile[64][65];
  __shared__ float sred[256], ssred[256];
  __shared__ float as_[64], cs_[64];
  int b = blockIdx.z, col0 = blockIdx.y * 64, s0 = blockIdx.x * 64;
  int t = threadIdx.x;
  int colL = t & 63, grp = t >> 6;
  {
    int col = col0 + colL;
    float s = 0.f, ss = 0.f;
    for (int row = grp * 32; row < grp * 32 + 32; ++row) {
      s += p2b[row * 512 + col];
      ss += p2b[row * 512 + 256 + col];
    }
    sred[grp * 64 + colL] = s;
    ssred[grp * 64 + colL] = ss;
  }
  __syncthreads();
  if (grp == 0) {
    float S = sred[colL] + sred[64 + colL] + sred[128 + colL] + sred[192 + colL];
    float SS = ssred[colL] + ssred[64 + colL] + ssred[128 + colL] + ssred[192 + colL];
    float mean = S / (float)Mm;
    float var = SS / (float)Mm - mean * mean;
    float a = g2[col0 + colL] * rsqrtf(var + BNEPS);
    as_[colL] = a;
    cs_[colL] = be2[col0 + colL] - mean * a;
  }
  __syncthreads();
  float a = as_[colL], c = cs_[colL];
  int sr = grp;
#pragma unroll
  for (int i = 0; i < 16; ++i) {
    int sl = sr * 16 + i;
    size_t q = (size_t)(b * Sn + s0 + sl);
    float v = valv[q * C2 + col0 + colL];
    tile[colL][sl] = fmaxf(0.f, a * v + c);
  }
  __syncthreads();
  int sl = t & 63, cr = t >> 6;
#pragma unroll
  for (int i = 0; i < 16; ++i) {
    int chl2 = i * 4 + cr;
    out[OUT_XYZ + ((size_t)(b * C2 + col0 + chl2)) * Sn + s0 + sl] = tile[chl2][sl];
  }
}

extern "C" void kernel_launch(void* const* d_in, const int* in_sizes, int n_in,
                              void* d_out, int out_size, void* d_ws, size_t ws_size,
                              hipStream_t stream) {
  (void)in_sizes; (void)n_in; (void)out_size; (void)ws_size;
  const float* xyz  = (const float*)d_in[0];
  const float* pts  = (const float*)d_in[1];
  const float* nxyz = (const float*)d_in[2];
  const float* W1   = (const float*)d_in[3];
  const float* b1   = (const float*)d_in[4];
  const float* g1   = (const float*)d_in[5];
  const float* be1  = (const float*)d_in[6];
  const float* W2   = (const float*)d_in[7];
  const float* b2   = (const float*)d_in[8];
  const float* g2   = (const float*)d_in[9];
  const float* be2  = (const float*)d_in[10];
  float* out = (float*)d_out;
  char* ws = (char*)d_ws;

  int*            idx    = (int*)(ws + OFF_IDX);
  unsigned short* ptsTbf = (unsigned short*)(ws + OFF_PTST);
  float*          part1  = (float*)(ws + OFF_P1);
  float*          part2  = (float*)(ws + OFF_P2);
  float*          p1b    = (float*)(ws + OFF_P1B);
  float*          p2b    = (float*)(ws + OFF_P2B);
  float*          bn1    = (float*)(ws + OFF_BN1);
  unsigned short* w2f    = (unsigned short*)(ws + OFF_W2F);
  unsigned short* w1f    = (unsigned short*)(ws + OFF_W1F);
  float*          valv   = (float*)(ws + OFF_VAL);

  k_knn<<<Qq + 784, 256, 0, stream>>>(xyz, nxyz, idx, pts, W1, W2, ptsTbf, out, w1f, w2f);
  k_mlp1s<<<NB_MLP, 256, 0, stream>>>(ptsTbf, xyz, nxyz, idx, w1f, b1, part1);
  k_red1a<<<128, 256, 0, stream>>>(part1, p1b);
  k_red1b<<<1, 256, 0, stream>>>(p1b, b1, g1, be1, bn1);
  k_m2f<<<NB_MLP, 256, 0, stream>>>(ptsTbf, xyz, nxyz, idx, w1f, bn1, w2f, b2, g2, part2, valv);
  k_red2a<<<128, 512, 0, stream>>>(part2, p2b);
  k_out<<<dim3(Sn / 64, C2 / 64, Bn), 256, 0, stream>>>(valv, p2b, g2, be2, out);
}

// Round 16
// 125.711 us; speedup vs baseline: 2.0656x; 1.0220x over previous
//
#include <hip/hip_runtime.h>
#include <stdint.h>

constexpr int Bn = 8, Nn = 4096, Sn = 1024, Cc = 64, KNN = 32, C1 = 128, C2 = 256;
constexpr int Qq = Bn * Sn;     // 8192 queries
constexpr int Mm = Qq * KNN;    // 262144 samples
constexpr int OUT_XYZ = Bn * Sn * 3;  // 24576 floats (output 0)
constexpr float BNEPS = 1e-5f;
constexpr unsigned RSEL = 9;    // sample order statistic -> E[candidates]~72

// ---------- ws layout ----------
constexpr size_t SZ_IDX  = (size_t)Qq * KNN * 4;        // 1 MB
constexpr size_t SZ_PTST = (size_t)Bn * Nn * Cc * 2;    // 4 MB (bf16)
constexpr int    NB_MLP  = Mm / 64;                     // 4096 blocks
constexpr size_t SZ_P1   = (size_t)NB_MLP * 256 * 4;    // 4 MB
constexpr size_t SZ_P2   = (size_t)NB_MLP * 512 * 4;    // 8 MB
constexpr size_t OFF_IDX  = 0;
constexpr size_t OFF_PTST = OFF_IDX + SZ_IDX;
constexpr size_t OFF_P1   = OFF_PTST + SZ_PTST;
constexpr size_t OFF_P2   = OFF_P1 + SZ_P1;
constexpr size_t OFF_P1B  = OFF_P2 + SZ_P2;
constexpr size_t OFF_P2B  = OFF_P1B + (size_t)128 * 256 * 4;
constexpr size_t OFF_BN1  = OFF_P2B + (size_t)128 * 512 * 4;
constexpr size_t OFF_W2F  = OFF_BN1 + 1024;                  // 64 KB
constexpr size_t OFF_W1F  = OFF_W2F + (size_t)32768 * 2;     // 24 KB
constexpr size_t OFF_VAL  = (OFF_W1F + (size_t)12288 * 2 + 255) & ~(size_t)255;  // extreme: 8 MB

typedef __attribute__((ext_vector_type(8))) __bf16 bf16x8;
typedef __attribute__((ext_vector_type(4))) float f32x4;

__device__ __forceinline__ unsigned short f2bf(float f) {
  unsigned u = __float_as_uint(f);
  u = u + 0x7FFFu + ((u >> 16) & 1u);   // RNE
  return (unsigned short)(u >> 16);
}

// ballot-aggregated histogram add (use only for CLUSTERED bins, e.g. fp exponent)
__device__ __forceinline__ void agg_hist(unsigned* hist, unsigned bin, bool valid, int lane) {
  bool todo = valid;
  while (true) {
    unsigned long long bm = __ballot(todo);
    if (bm == 0ull) break;
    int first = __ffsll(bm) - 1;
    unsigned b = (unsigned)__shfl((int)bin, first);
    unsigned long long m = __ballot(todo && bin == b);
    if (lane == first) atomicAdd(&hist[b], (unsigned)__popcll(m));
    if (todo && bin == b) todo = false;
  }
}

// ---------- kNN (blocks < Qq) + fused prep (blocks >= Qq; outputs consumed only by LATER kernels) ----------
__global__ __launch_bounds__(256) void k_knn(const float* __restrict__ xyz,
                                             const float* __restrict__ nxyz,
                                             int* __restrict__ idxout,
                                             const float* __restrict__ pts,
                                             const float* __restrict__ W1,
                                             const float* __restrict__ W2,
                                             unsigned short* __restrict__ ptsTbf,
                                             float* __restrict__ outdst,
                                             unsigned short* __restrict__ w1f,
                                             unsigned short* __restrict__ w2f) {
  int t = threadIdx.x;
  if (blockIdx.x >= (unsigned)Qq) {          // ---- prep branch ----
    int blk = blockIdx.x - Qq;
    if (blk < 512) {                         // points [B,C,N] f32 -> [B,N,C] bf16
      __shared__ float tile[64][65];
      int b = blk >> 6, n0 = (blk & 63) * 64;
      int cl = t & 63, rw = t >> 6;
#pragma unroll
      for (int i = 0; i < 16; ++i) {
        int c = i * 4 + rw;
        tile[cl][c] = pts[((size_t)b * Cc + c) * Nn + n0 + cl];
      }
      __syncthreads();
#pragma unroll
      for (int i = 0; i < 16; ++i) {
        int nf = i * 4 + rw;
        ptsTbf[((size_t)b * Nn + n0 + nf) * Cc + cl] = f2bf(tile[nf][cl]);
      }
    } else if (blk < 608) {                  // copy new_xyz to output 0
      int i = t + (blk - 512) * 256;
      if (i < OUT_XYZ) outdst[i] = nxyz[i];
    } else if (blk < 656) {                  // W1 -> bf16 B-frags, K pad 96
      int u = t + (blk - 608) * 256;
      int j = u & 7, lane = (u >> 3) & 63, rest = u >> 9;
      int ks = rest % 3, nt = rest / 3;
      int ch = nt * 16 + (lane & 15);
      int k = ks * 32 + (lane >> 4) * 8 + j;
      w1f[u] = (k < 70) ? f2bf(W1[ch * 70 + k]) : (unsigned short)0;
    } else {                                 // W2 -> bf16 B-frags
      int u = t + (blk - 656) * 256;
      int j = u & 7, lane = (u >> 3) & 63, ks = (u >> 9) & 3, ntile = u >> 11;
      int col = ntile * 16 + (lane & 15);
      int k = ks * 32 + (lane >> 4) * 8 + j;
      w2f[u] = f2bf(W2[col * C1 + k]);
    }
    return;
  }
  // ---- knn branch ----
  int q = blockIdx.x, b = q >> 10;
  int lane = t & 63, w = t >> 6;
  const float4* xb4 = reinterpret_cast<const float4*>(xyz + (size_t)b * Nn * 3);
  float qx = nxyz[q * 3 + 0], qy = nxyz[q * 3 + 1], qz = nxyz[q * 3 + 2];
  unsigned key[16];
  {
#pragma clang fp contract(off)
    float sqq = (qx * qx + qy * qy) + qz * qz;
#pragma unroll
    for (int h = 0; h < 2; ++h) {            // 2 half-chunks of 8 points
      float fl[24];
#pragma unroll
      for (int j = 0; j < 6; ++j) {
        float4 v = xb4[t * 12 + h * 6 + j];
        fl[4 * j + 0] = v.x; fl[4 * j + 1] = v.y; fl[4 * j + 2] = v.z; fl[4 * j + 3] = v.w;
      }
#pragma unroll
      for (int i = 0; i < 8; ++i) {
        float xl = fl[3 * i], yl = fl[3 * i + 1], zl = fl[3 * i + 2];
        float sqp = (xl * xl + yl * yl) + zl * zl;
        float dot = __builtin_fmaf(qz, zl, __builtin_fmaf(qy, yl, qx * xl));
        float d = (sqq + sqp) - 2.0f * dot;
        unsigned u = __float_as_uint(d);
        key[h * 8 + i] = (u & 0x80000000u) ? ~u : (u | 0x80000000u);   // monotone map
      }
    }
  }
  __shared__ unsigned long long buf64[256];
  __shared__ unsigned hist[256];
  __shared__ unsigned hist2[256];
  __shared__ unsigned wsum[4];
  __shared__ unsigned sel_bin, sel_off, cnt, ovf, thrU, tieflag;
  __shared__ unsigned eqcnt;
  __shared__ int eqbuf[128];

  unsigned s0 = key[0], s1 = key[8];   // samples: points 16t and 16t+8
  hist[t] = 0;
  hist2[t] = 0;
  if (t == 0) { cnt = 0; ovf = 0; thrU = 0xFFFFFFFFu; tieflag = 0; }
  __syncthreads();
  // S1: top byte of samples (exponent-clustered -> aggregated adds)
  agg_hist(hist, s0 >> 24, true, lane);
  agg_hist(hist, s1 >> 24, true, lane);
  __syncthreads();
  {
    unsigned h = hist[t], v = h;
#pragma unroll
    for (int off = 1; off < 64; off <<= 1) {
      unsigned o = __shfl_up(v, off);
      if (lane >= off) v += o;
    }
    if (lane == 63) wsum[w] = v;
    __syncthreads();
    unsigned woff = 0;
    for (int ww = 0; ww < w; ++ww) woff += wsum[ww];
    v += woff;
    unsigned vex = v - h;
    if (vex < RSEL && RSEL <= v) { sel_bin = (unsigned)t; sel_off = RSEL - vex; }
    __syncthreads();
  }
  unsigned sbin = sel_bin, srem = sel_off;
  // S2: byte 2 of samples in sbin (uniform bins -> plain atomics)
  if ((s0 >> 24) == sbin) atomicAdd(&hist2[(s0 >> 16) & 255u], 1u);
  if ((s1 >> 24) == sbin) atomicAdd(&hist2[(s1 >> 16) & 255u], 1u);
  __syncthreads();
  {
    unsigned h = hist2[t], v = h;
#pragma unroll
    for (int off = 1; off < 64; off <<= 1) {
      unsigned o = __shfl_up(v, off);
      if (lane >= off) v += o;
    }
    if (lane == 63) wsum[w] = v;
    __syncthreads();
    unsigned woff = 0;
    for (int ww = 0; ww < w; ++ww) woff += wsum[ww];
    v += woff;
    unsigned vex = v - h;
    if (vex < srem && srem <= v) {
      unsigned p16 = (sbin << 8) | (unsigned)t;
      thrU = (p16 >= 0xFFFFu) ? 0xFFFFFFFFu : ((p16 + 1u) << 16);
    }
    __syncthreads();
  }
  unsigned U = thrU;
  // compact candidates (key < U), ballot-aggregated
#pragma unroll
  for (int i = 0; i < 16; ++i) {
    bool take = key[i] < U;
    unsigned long long m = __ballot(take);
    if (m == 0ull) continue;
    unsigned base = 0;
    if (lane == 0) base = atomicAdd(&cnt, (unsigned)__popcll(m));
    base = (unsigned)__shfl((int)base, 0);
    if (take) {
      unsigned off = base + (unsigned)__popcll(m & ((1ull << lane) - 1ull));
      if (off < 256u)
        buf64[off] = ((unsigned long long)key[i] << 32) | (unsigned)(t * 16 + i);
      else
        ovf = 1;
    }
  }
  __syncthreads();
  unsigned ncnt = cnt;
  if (!ovf && ncnt >= (unsigned)KNN && ncnt <= 256u) {
    int nc = (int)ncnt;
    const unsigned* keyhw = reinterpret_cast<const unsigned*>(buf64);  // [2i]=idx, [2i+1]=key
    int r = 0;
    bool own = false;
    int cid = 0;
    if (nc <= 64) {
      // 4-way wave-split: candidate = lane; wave w scans source lanes [16w,16w+16)
      unsigned mykey = (lane < nc) ? keyhw[2 * lane + 1] : 0xFFFFFFFFu;
      int partial = 0;
      int base = w * 16;
#pragma unroll
      for (int ii = 0; ii < 16; ++ii) {
        int i = base + ii;
        bool inr = (i < nc);
        unsigned ok = (unsigned)__builtin_amdgcn_readlane((int)mykey, i);
        partial += (inr && ok < mykey);
      }
      hist[w * 64 + lane] = (unsigned)partial;
      __syncthreads();
      if (t < 64) {
        r = (int)(hist[t] + hist[64 + t] + hist[128 + t] + hist[192 + t]);
        cid = t;
        own = (t < nc);
      }
    } else if (nc <= 128) {
      // 2-way split: candidate = t&127; half t>>7 scans its 64-chunk
      cid = t & 127;
      bool haveC = (cid < nc);
      unsigned mykey = haveC ? keyhw[2 * cid + 1] : 0xFFFFFFFFu;
      int partial = 0;
      int c = t >> 7;
      if (c * 64 < nc) {
        int ci = c * 64 + lane;
        unsigned bk = (ci < nc) ? keyhw[2 * ci + 1] : 0xFFFFFFFFu;
#pragma unroll
        for (int i = 0; i < 64; ++i) {
          unsigned ok = (unsigned)__builtin_amdgcn_readlane((int)bk, i);
          partial += (ok < mykey);
        }
      }
      hist[t] = (unsigned)partial;
      __syncthreads();
      if (t < 128) {
        r = (int)(hist[t] + hist[t + 128]);
        own = haveC;
      }
    } else {
      // full: candidate = t, scan all chunks
      cid = t;
      bool haveC = (t < nc);
      unsigned mykey = haveC ? keyhw[2 * t + 1] : 0xFFFFFFFFu;
      int nchunk = (nc + 63) >> 6;
      for (int c = 0; c < nchunk; ++c) {
        int ci = c * 64 + lane;
        unsigned bk = (ci < nc) ? keyhw[2 * ci + 1] : 0xFFFFFFFFu;
#pragma unroll
        for (int i = 0; i < 64; ++i) {
          unsigned ok = (unsigned)__builtin_amdgcn_readlane((int)bk, i);
          r += (ok < mykey);
        }
      }
      own = haveC;
    }
    // tie detection: strict-less u32 ranks collide iff keys tie
    hist2[t] = 0;
    __syncthreads();
    if (own) atomicAdd(&hist2[r], 1u);
    __syncthreads();
    if (hist2[t] > 1u) tieflag = 1;
    __syncthreads();
    if (tieflag) {   // rare: exact u64 redo, generic (candidate = t)
      bool own2 = (t < nc);
      unsigned long long my64 = own2 ? buf64[t] : ~0ull;
      int rr = 0;
      int nchunk = (nc + 63) >> 6;
      for (int c = 0; c < nchunk; ++c) {
        int ci = c * 64 + lane;
        unsigned long long v = (ci < nc) ? buf64[ci] : ~0ull;
        unsigned vlo = (unsigned)v, vhi = (unsigned)(v >> 32);
#pragma unroll
        for (int i = 0; i < 64; ++i) {
          unsigned olo = (unsigned)__builtin_amdgcn_readlane((int)vlo, i);
          unsigned ohi = (unsigned)__builtin_amdgcn_readlane((int)vhi, i);
          unsigned long long o = ((unsigned long long)ohi << 32) | olo;
          rr += (o < my64);
        }
      }
      if (own2 && rr < KNN) idxout[q * KNN + rr] = (int)keyhw[2 * t];
    } else {
      if (own && r < KNN) idxout[q * KNN + r] = (int)keyhw[2 * cid];
    }
  } else {
    // fallback: full 4-pass radix (round-4 proven path)
    unsigned prefix = 0, remaining = (unsigned)KNN;
    if (t == 0) { cnt = 0; eqcnt = 0; }
#pragma unroll
    for (int shift = 24; shift >= 0; shift -= 8) {
      hist[t] = 0;
      __syncthreads();
      unsigned himask = (shift == 24) ? 0u : (0xFFFFFFFFu << ((shift + 8) & 31));
#pragma unroll
      for (int i = 0; i < 16; ++i)
        if ((key[i] & himask) == prefix)
          atomicAdd(&hist[(key[i] >> shift) & 255], 1u);
      __syncthreads();
      unsigned h = hist[t], v = h;
#pragma unroll
      for (int off = 1; off < 64; off <<= 1) {
        unsigned o = __shfl_up(v, off);
        if (lane >= off) v += o;
      }
      if (lane == 63) wsum[w] = v;
      __syncthreads();
      unsigned woff = 0;
      for (int ww = 0; ww < w; ++ww) woff += wsum[ww];
      v += woff;
      unsigned vex = v - h;
      if (vex < remaining && remaining <= v) { sel_bin = (unsigned)t; sel_off = vex; }
      __syncthreads();
      prefix |= sel_bin << shift;
      remaining -= sel_off;
    }
#pragma unroll
    for (int i = 0; i < 16; ++i) {
      int p = t * 16 + i;
      if (key[i] < prefix) {
        unsigned pos = atomicAdd(&cnt, 1u);
        idxout[q * KNN + pos] = p;
      } else if (key[i] == prefix) {
        unsigned e = atomicAdd(&eqcnt, 1u);
        if (e < 128u) eqbuf[e] = p;
      }
    }
    __syncthreads();
    if (t == 0) {
      int n = (int)min(eqcnt, 128u);
      for (int a = 1; a < n; ++a) {
        int x = eqbuf[a], bi = a - 1;
        while (bi >= 0 && eqbuf[bi] > x) { eqbuf[bi + 1] = eqbuf[bi]; --bi; }
        eqbuf[bi + 1] = x;
      }
      int base = (int)cnt;
      for (int j = 0; j < (int)remaining; ++j) idxout[q * KNN + base + j] = eqbuf[j];
    }
  }
}

// ---------- shared staging helper: gather tile -> zs (swz (j&7)<<4) ----------
__device__ __forceinline__ void stage_gather(unsigned short* zs,
                                             const unsigned short* __restrict__ ptsTbf,
                                             const float* __restrict__ xyz,
                                             const float* __restrict__ nxyz,
                                             const int* __restrict__ idx,
                                             int m0, int b, int t) {
  int j = t >> 2, part = t & 3;
  int m = m0 + j;
  int pid = idx[m];
  const uint4* src =
      reinterpret_cast<const uint4*>(ptsTbf + ((size_t)b * Nn + pid) * Cc + part * 16);
  char* zc = reinterpret_cast<char*>(zs);
  int base = j * 256, swz = (j & 7) << 4;
  uint4 s0 = src[0], s1 = src[1];
  *reinterpret_cast<uint4*>(zc + ((base + part * 32) ^ swz)) = s0;
  *reinterpret_cast<uint4*>(zc + ((base + part * 32 + 16) ^ swz)) = s1;
  uint4 ex = make_uint4(0u, 0u, 0u, 0u);
  if (part == 0) {
    const float* xp = xyz + ((size_t)b * Nn + pid) * 3;
    int s = (m >> 5) & (Sn - 1);
    const float* qp = nxyz + (size_t)(b * Sn + s) * 3;
    ex.x = (unsigned)f2bf(xp[0]) | ((unsigned)f2bf(xp[1]) << 16);
    ex.y = (unsigned)f2bf(xp[2]) | ((unsigned)f2bf(qp[0]) << 16);
    ex.z = (unsigned)f2bf(qp[1]) | ((unsigned)f2bf(qp[2]) << 16);
  }
  *reinterpret_cast<uint4*>(zc + ((base + (8 + part) * 16) ^ swz)) = ex;
}

// ---------- layer1 stats-only: gather + W1 MFMA -> sum/sumsq partials ----------
__global__ __launch_bounds__(256) void k_mlp1s(const unsigned short* __restrict__ ptsTbf,
                                               const float* __restrict__ xyz,
                                               const float* __restrict__ nxyz,
                                               const int* __restrict__ idx,
                                               const unsigned short* __restrict__ w1f,
                                               const float* __restrict__ b1,
                                               float* __restrict__ part1) {
  __shared__ unsigned short zs[64 * 128];
  int t = threadIdx.x;
  int m0 = blockIdx.x * 64;
  int b = m0 >> 15;
  int lane = t & 63, w = t >> 6;
  bf16x8 bfrag[2][3];
  {
    const uint4* wp = reinterpret_cast<const uint4*>(w1f);
#pragma unroll
    for (int nt = 0; nt < 2; ++nt)
#pragma unroll
      for (int ks = 0; ks < 3; ++ks)
        bfrag[nt][ks] = __builtin_bit_cast(bf16x8, wp[((w * 2 + nt) * 3 + ks) * 64 + lane]);
  }
  stage_gather(zs, ptsTbf, xyz, nxyz, idx, m0, b, t);
  __syncthreads();
  f32x4 acc[4][2];
#pragma unroll
  for (int mt = 0; mt < 4; ++mt)
#pragma unroll
    for (int nt = 0; nt < 2; ++nt) acc[mt][nt] = f32x4{0.f, 0.f, 0.f, 0.f};
  int r15 = lane & 15, rhi = lane >> 4;
  const char* zc = reinterpret_cast<const char*>(zs);
#pragma unroll
  for (int mt = 0; mt < 4; ++mt) {
    int row = mt * 16 + r15;
    bf16x8 af[3];
#pragma unroll
    for (int ks = 0; ks < 3; ++ks)
      af[ks] = __builtin_bit_cast(
          bf16x8, *reinterpret_cast<const uint4*>(
                      zc + ((row * 256 + ks * 64 + rhi * 16) ^ ((row & 7) << 4))));
#pragma unroll
    for (int nt = 0; nt < 2; ++nt)
#pragma unroll
      for (int ks = 0; ks < 3; ++ks)
        acc[mt][nt] =
            __builtin_amdgcn_mfma_f32_16x16x32_bf16(af[ks], bfrag[nt][ks], acc[mt][nt], 0, 0, 0);
  }
#pragma unroll
  for (int nt = 0; nt < 2; ++nt) {
    int col = w * 32 + nt * 16 + r15;
    float bv = b1[col];
    float s = 0.f, ss = 0.f;
#pragma unroll
    for (int mt = 0; mt < 4; ++mt)
#pragma unroll
      for (int rg = 0; rg < 4; ++rg) {
        float v = acc[mt][nt][rg] + bv;
        s += v; ss += v * v;
      }
    s += __shfl_xor(s, 16); s += __shfl_xor(s, 32);
    ss += __shfl_xor(ss, 16); ss += __shfl_xor(ss, 32);
    if (lane < 16) {
      part1[(size_t)blockIdx.x * 256 + col] = s;
      part1[(size_t)blockIdx.x * 256 + 128 + col] = ss;
    }
  }
}

// ---------- stats reduce (layer1) ----------
__global__ __launch_bounds__(256) void k_red1a(const float* __restrict__ part1,
                                               float* __restrict__ p1b) {
  int t = threadIdx.x, r = blockIdx.x;       // 128 blocks x 32 rows
  float acc = 0.f;
  for (int row = r * 32; row < r * 32 + 32; ++row)
    acc += part1[(size_t)row * 256 + t];
  p1b[r * 256 + t] = acc;
}
// bn1[t] = a; bn1[128+t] = a*b1 + be1 - mean*a  (b1 folded so fused kernel skips it)
__global__ __launch_bounds__(256) void k_red1b(const float* __restrict__ p1b,
                                               const float* __restrict__ b1,
                                               const float* __restrict__ g1,
                                               const float* __restrict__ be1,
                                               float* __restrict__ bn1) {
  __shared__ float lds[256];
  int t = threadIdx.x;
  float acc = 0.f;
  for (int row = 0; row < 128; ++row) acc += p1b[row * 256 + t];
  lds[t] = acc;
  __syncthreads();
  if (t < 128) {
    float sum = lds[t], ss = lds[128 + t];
    float mean = sum / (float)Mm;
    float var = ss / (float)Mm - mean * mean;
    float a = g1[t] * rsqrtf(var + BNEPS);
    bn1[t] = a;
    bn1[128 + t] = a * b1[t] + (be1[t] - mean * a);
  }
}

// ---------- fused layer1+layer2: gather -> W1 MFMA -> BN1+relu -> W2 MFMA -> stats+extreme ----------
__global__ __launch_bounds__(256) void k_m2f(const unsigned short* __restrict__ ptsTbf,
                                             const float* __restrict__ xyz,
                                             const float* __restrict__ nxyz,
                                             const int* __restrict__ idx,
                                             const unsigned short* __restrict__ w1f,
                                             const float* __restrict__ bn1c,
                                             const unsigned short* __restrict__ w2f,
                                             const float* __restrict__ b2,
                                             const float* __restrict__ g2,
                                             float* __restrict__ part2,
                                             float* __restrict__ valv) {
  __shared__ unsigned short zs[64 * 128];   // gather tile, then z1 tile (both swz (row&7)<<4)
  __shared__ float bns[256];
  int t = threadIdx.x;
  int m0 = blockIdx.x * 64;
  int b = m0 >> 15;
  int lane = t & 63, w = t >> 6;
  bns[t] = bn1c[t];
  bf16x8 b1frag[2][3];
  {
    const uint4* wp = reinterpret_cast<const uint4*>(w1f);
#pragma unroll
    for (int nt = 0; nt < 2; ++nt)
#pragma unroll
      for (int ks = 0; ks < 3; ++ks)
        b1frag[nt][ks] = __builtin_bit_cast(bf16x8, wp[((w * 2 + nt) * 3 + ks) * 64 + lane]);
  }
  stage_gather(zs, ptsTbf, xyz, nxyz, idx, m0, b, t);
  __syncthreads();
  int r15 = lane & 15, rhi = lane >> 4;
  f32x4 acc1[4][2];
#pragma unroll
  for (int mt = 0; mt < 4; ++mt)
#pragma unroll
    for (int nt = 0; nt < 2; ++nt) acc1[mt][nt] = f32x4{0.f, 0.f, 0.f, 0.f};
  {
    const char* zc = reinterpret_cast<const char*>(zs);
#pragma unroll
    for (int mt = 0; mt < 4; ++mt) {
      int row = mt * 16 + r15;
      bf16x8 af[3];
#pragma unroll
      for (int ks = 0; ks < 3; ++ks)
        af[ks] = __builtin_bit_cast(
            bf16x8, *reinterpret_cast<const uint4*>(
                        zc + ((row * 256 + ks * 64 + rhi * 16) ^ ((row & 7) << 4))));
#pragma unroll
      for (int nt = 0; nt < 2; ++nt)
#pragma unroll
        for (int ks = 0; ks < 3; ++ks)
          acc1[mt][nt] = __builtin_amdgcn_mfma_f32_16x16x32_bf16(af[ks], b1frag[nt][ks],
                                                                 acc1[mt][nt], 0, 0, 0);
    }
  }
  __syncthreads();   // gather tile reads done; reuse zs for z1
  {
    char* zcw = reinterpret_cast<char*>(zs);
#pragma unroll
    for (int nt = 0; nt < 2; ++nt) {
      int col = w * 32 + nt * 16 + r15;
      float a = bns[col], c = bns[128 + col];
#pragma unroll
      for (int mt = 0; mt < 4; ++mt)
#pragma unroll
        for (int rg = 0; rg < 4; ++rg) {
          int row = mt * 16 + rhi * 4 + rg;
          float z = fmaxf(0.f, a * acc1[mt][nt][rg] + c);
          *reinterpret_cast<unsigned short*>(
              zcw + ((row * 256 + col * 2) ^ ((row & 7) << 4))) = f2bf(z);
        }
    }
  }
  __syncthreads();
  // W2 fragments (loaded after acc1 is dead to cap VGPR)
  bf16x8 b2frag[4][4];
  {
    const uint4* wp = reinterpret_cast<const uint4*>(w2f) + (size_t)(w * 4) * 4 * 64 + lane;
#pragma unroll
    for (int nt = 0; nt < 4; ++nt)
#pragma unroll
      for (int ks = 0; ks < 4; ++ks)
        b2frag[nt][ks] = __builtin_bit_cast(bf16x8, wp[(nt * 4 + ks) * 64]);
  }
  f32x4 acc[4][4];
#pragma unroll
  for (int mt = 0; mt < 4; ++mt)
#pragma unroll
    for (int nt = 0; nt < 4; ++nt) acc[mt][nt] = f32x4{0.f, 0.f, 0.f, 0.f};
  {
    const char* zc = reinterpret_cast<const char*>(zs);
#pragma unroll
    for (int mt = 0; mt < 4; ++mt) {
      int row = mt * 16 + r15;
      bf16x8 af[4];
#pragma unroll
      for (int ks = 0; ks < 4; ++ks)
        af[ks] = __builtin_bit_cast(
            bf16x8, *reinterpret_cast<const uint4*>(
                        zc + ((row * 256 + ks * 64 + rhi * 16) ^ ((row & 7) << 4))));
#pragma unroll
      for (int nt = 0; nt < 4; ++nt)
#pragma unroll
        for (int ks = 0; ks < 4; ++ks)
          acc[mt][nt] = __builtin_amdgcn_mfma_f32_16x16x32_bf16(af[ks], b2frag[nt][ks],
                                                                acc[mt][nt], 0, 0, 0);
    }
  }
  int wn0 = w * 64;
  int q0 = m0 >> 5;   // 2 queries per block (32 samples each)
#pragma unroll
  for (int nt = 0; nt < 4; ++nt) {
    int col = wn0 + nt * 16 + r15;
    float bv = b2[col];
    bool pos = (g2[col] >= 0.0f);   // sign(a2) == sign(g2), rsqrt > 0
    float s = 0.f, ss = 0.f;
    float mA = -3.0e38f, mB = -3.0e38f, nA = 3.0e38f, nB = 3.0e38f;
#pragma unroll
    for (int mt = 0; mt < 4; ++mt)
#pragma unroll
      for (int rg = 0; rg < 4; ++rg) {
        float v = acc[mt][nt][rg] + bv;
        s += v; ss += v * v;
        if (mt < 2) { mA = fmaxf(mA, v); nA = fminf(nA, v); }
        else        { mB = fmaxf(mB, v); nB = fminf(nB, v); }
      }
    float vA = pos ? mA : nA, vB = pos ? mB : nB;
    s += __shfl_xor(s, 16); s += __shfl_xor(s, 32);
    ss += __shfl_xor(ss, 16); ss += __shfl_xor(ss, 32);
    if (pos) {
      vA = fmaxf(vA, __shfl_xor(vA, 16)); vA = fmaxf(vA, __shfl_xor(vA, 32));
      vB = fmaxf(vB, __shfl_xor(vB, 16)); vB = fmaxf(vB, __shfl_xor(vB, 32));
    } else {
      vA = fminf(vA, __shfl_xor(vA, 16)); vA = fminf(vA, __shfl_xor(vA, 32));
      vB = fminf(vB, __shfl_xor(vB, 16)); vB = fminf(vB, __shfl_xor(vB, 32));
    }
    if (lane < 16) {
      part2[(size_t)blockIdx.x * 512 + col] = s;
      part2[(size_t)blockIdx.x * 512 + 256 + col] = ss;
    }
    if (lane < 32) {
      int q = q0 + (lane >> 4);
      valv[(size_t)q * C2 + col] = (lane < 16) ? vA : vB;
    }
  }
}

// ---------- stats reduce (layer2, stage a only) ----------
__global__ __launch_bounds__(512) void k_red2a(const float* __restrict__ part2,
                                               float* __restrict__ p2b) {
  int t = threadIdx.x, r = blockIdx.x;       // 128 blocks x 32 rows
  float acc = 0.f;
  for (int row = r * 32; row < r * 32 + 32; ++row)
    acc += part2[(size_t)row * 512 + t];
  p2b[r * 512 + t] = acc;
}

// ---------- epilogue: derive bn2 slice from p2b; out = relu(a2*val + c2), transposed ----------
__global__ __launch_bounds__(256) void k_out(const float* __restrict__ valv,
                                             const float* __restrict__ p2b,
                                             const float* __restrict__ g2,
                                             const float* __restrict__ be2,
                                             float* __restrict__ out) {
  __shared__ float tile[64][65];
  __shared__ float sred[256], ssred[256];
  __shared__ float as_[64], cs_[64];
  int b = blockIdx.z, col0 = blockIdx.y * 64, s0 = blockIdx.x * 64;
  int t = threadIdx.x;
  int colL = t & 63, grp = t >> 6;
  {
    int col = col0 + colL;
    float s = 0.f, ss = 0.f;
    for (int row = grp * 32; row < grp * 32 + 32; ++row) {
      s += p2b[row * 512 + col];
      ss += p2b[row * 512 + 256 + col];
    }
    sred[grp * 64 + colL] = s;
    ssred[grp * 64 + colL] = ss;
  }
  __syncthreads();
  if (grp == 0) {
    float S = sred[colL] + sred[64 + colL] + sred[128 + colL] + sred[192 + colL];
    float SS = ssred[colL] + ssred[64 + colL] + ssred[128 + colL] + ssred[192 + colL];
    float mean = S / (float)Mm;
    float var = SS / (float)Mm - mean * mean;
    float a = g2[col0 + colL] * rsqrtf(var + BNEPS);
    as_[colL] = a;
    cs_[colL] = be2[col0 + colL] - mean * a;
  }
  __syncthreads();
  float a = as_[colL], c = cs_[colL];
  int sr = grp;
#pragma unroll
  for (int i = 0; i < 16; ++i) {
    int sl = sr * 16 + i;
    size_t q = (size_t)(b * Sn + s0 + sl);
    float v = valv[q * C2 + col0 + colL];
    tile[colL][sl] = fmaxf(0.f, a * v + c);
  }
  __syncthreads();
  int sl = t & 63, cr = t >> 6;
#pragma unroll
  for (int i = 0; i < 16; ++i) {
    int chl2 = i * 4 + cr;
    out[OUT_XYZ + ((size_t)(b * C2 + col0 + chl2)) * Sn + s0 + sl] = tile[chl2][sl];
  }
}

extern "C" void kernel_launch(void* const* d_in, const int* in_sizes, int n_in,
                              void* d_out, int out_size, void* d_ws, size_t ws_size,
                              hipStream_t stream) {
  (void)in_sizes; (void)n_in; (void)out_size; (void)ws_size;
  const float* xyz  = (const float*)d_in[0];
  const float* pts  = (const float*)d_in[1];
  const float* nxyz = (const float*)d_in[2];
  const float* W1   = (const float*)d_in[3];
  const float* b1   = (const float*)d_in[4];
  const float* g1   = (const float*)d_in[5];
  const float* be1  = (const float*)d_in[6];
  const float* W2   = (const float*)d_in[7];
  const float* b2   = (const float*)d_in[8];
  const float* g2   = (const float*)d_in[9];
  const float* be2  = (const float*)d_in[10];
  float* out = (float*)d_out;
  char* ws = (char*)d_ws;

  int*            idx    = (int*)(ws + OFF_IDX);
  unsigned short* ptsTbf = (unsigned short*)(ws + OFF_PTST);
  float*          part1  = (float*)(ws + OFF_P1);
  float*          part2  = (float*)(ws + OFF_P2);
  float*          p1b    = (float*)(ws + OFF_P1B);
  float*          p2b    = (float*)(ws + OFF_P2B);
  float*          bn1    = (float*)(ws + OFF_BN1);
  unsigned short* w2f    = (unsigned short*)(ws + OFF_W2F);
  unsigned short* w1f    = (unsigned short*)(ws + OFF_W1F);
  float*          valv   = (float*)(ws + OFF_VAL);

  k_knn<<<Qq + 784, 256, 0, stream>>>(xyz, nxyz, idx, pts, W1, W2, ptsTbf, out, w1f, w2f);
  k_mlp1s<<<NB_MLP, 256, 0, stream>>>(ptsTbf, xyz, nxyz, idx, w1f, b1, part1);
  k_red1a<<<128, 256, 0, stream>>>(part1, p1b);
  k_red1b<<<1, 256, 0, stream>>>(p1b, b1, g1, be1, bn1);
  k_m2f<<<NB_MLP, 256, 0, stream>>>(ptsTbf, xyz, nxyz, idx, w1f, bn1, w2f, b2, g2, part2, valv);
  k_red2a<<<128, 512, 0, stream>>>(part2, p2b);
  k_out<<<dim3(Sn / 64, C2 / 64, Bn), 256, 0, stream>>>(valv, p2b, g2, be2, out);
}